// Round 2
// baseline (386.530 us; speedup 1.0000x reference)
//
#include <hip/hip_runtime.h>
#include <math.h>

#define B 64
#define P 16800
#define O 64
#define NCHUNK 66          // ceil(16800/256)
#define THRESH 0.35f
#define VALID_T 0.2f
#define HB 4096            // coarse hist bins = top 12 bits of float bits (rank >= 0)
#define HSHIFT 20
#define CAP 4096           // candidate buffer capacity in kE
#define TG 8               // truths per kB block

__device__ __forceinline__ float smooth_l1(float x) {
    float ax = fabsf(x);
    return ax < 1.f ? 0.5f * ax * ax : ax - 0.5f;
}

// ---------------- Kernel A: per-prior best truth (argmax over O, first-max tie-break)
__global__ void kA_best_truth(const float* __restrict__ priors,
                              const float* __restrict__ targets,
                              float* __restrict__ bt_ov, int* __restrict__ bt_idx) {
    int chunk = blockIdx.x % NCHUNK;
    int b = blockIdx.x / NCHUNK;
    __shared__ float tg[O * 15];
    for (int i = threadIdx.x; i < O * 15; i += blockDim.x) tg[i] = targets[b * O * 15 + i];
    __syncthreads();
    int p = chunk * 256 + threadIdx.x;
    if (p >= P) return;
    float4 pr = ((const float4*)priors)[p];
    float px1 = pr.x - pr.z * 0.5f, py1 = pr.y - pr.w * 0.5f;
    float px2 = pr.x + pr.z * 0.5f, py2 = pr.y + pr.w * 0.5f;
    float area_b = (px2 - px1) * (py2 - py1);
    float best = -1.f; int bi = 0;
    for (int o = 0; o < O; ++o) {
        const float* t = &tg[o * 15];
        float w = fmaxf(fminf(t[2], px2) - fmaxf(t[0], px1), 0.f);
        float h = fmaxf(fminf(t[3], py2) - fmaxf(t[1], py1), 0.f);
        float inter = w * h;
        float area_a = (t[2] - t[0]) * (t[3] - t[1]);
        float iou = inter / (area_a + area_b - inter);
        if (iou > best) { best = iou; bi = o; }   // strict >: first max wins (jnp.argmax)
    }
    bt_ov[b * P + p] = best;
    bt_idx[b * P + p] = bi;
}

// ---------------- Kernel B: per-truth best prior. Grid B x (O/TG); each block covers
// the ENTIRE prior range for TG truths -> priors traffic 512x268KB not 4096x268KB.
__global__ void kB_best_prior(const float* __restrict__ priors,
                              const float* __restrict__ targets,
                              int* __restrict__ bp_idx, int* __restrict__ bp_valid) {
    int g = blockIdx.x % (O / TG);
    int b = blockIdx.x / (O / TG);
    __shared__ float tb[TG][5];   // x1,y1,x2,y2,area
    if (threadIdx.x < TG * 5) {
        int o = threadIdx.x / 5, c = threadIdx.x % 5;
        const float* t = &targets[(b * O + g * TG + o) * 15];
        tb[o][c] = (c < 4) ? t[c] : (t[2] - t[0]) * (t[3] - t[1]);
    }
    __syncthreads();
    unsigned long long key[TG];
#pragma unroll
    for (int o = 0; o < TG; ++o) key[o] = 0ULL;
    for (int p = threadIdx.x; p < P; p += 256) {
        float4 pr = ((const float4*)priors)[p];
        float px1 = pr.x - pr.z * 0.5f, py1 = pr.y - pr.w * 0.5f;
        float px2 = pr.x + pr.z * 0.5f, py2 = pr.y + pr.w * 0.5f;
        float area_b = (px2 - px1) * (py2 - py1);
        unsigned pkey = 0xFFFFFFFFu - (unsigned)p;   // ties -> smaller p wins
#pragma unroll
        for (int o = 0; o < TG; ++o) {
            float w = fmaxf(fminf(tb[o][2], px2) - fmaxf(tb[o][0], px1), 0.f);
            float h = fmaxf(fminf(tb[o][3], py2) - fmaxf(tb[o][1], py1), 0.f);
            float inter = w * h;
            float iou = inter / (tb[o][4] + area_b - inter);
            unsigned long long kk = ((unsigned long long)__float_as_uint(iou) << 32) | pkey;
            if (kk > key[o]) key[o] = kk;
        }
    }
    __shared__ unsigned long long red[256];
    for (int o = 0; o < TG; ++o) {
        red[threadIdx.x] = key[o];
        __syncthreads();
        for (int s = 128; s > 0; s >>= 1) {
            if (threadIdx.x < s) {
                unsigned long long a = red[threadIdx.x], c = red[threadIdx.x + s];
                red[threadIdx.x] = a > c ? a : c;
            }
            __syncthreads();
        }
        if (threadIdx.x == 0) {
            unsigned long long kk = red[0];
            int pp = (int)(0xFFFFFFFFu - (unsigned)(kk & 0xFFFFFFFFu));
            float iou = __uint_as_float((unsigned)(kk >> 32));
            bp_idx[b * O + g * TG + o] = pp;
            bp_valid[b * O + g * TG + o] = (iou >= VALID_T) ? 1 : 0;
        }
        __syncthreads();
    }
}

// ---------------- Kernel C: scatter overrides, one wave per row.
// numpy last-write-wins for duplicate bp_idx; bt_ov values read PRE-scatter.
__global__ void kC_scatter(const int* __restrict__ bp_idx, const int* __restrict__ bp_valid,
                           float* __restrict__ bt_ov, int* __restrict__ bt_idx,
                           int* __restrict__ any_valid) {
    int b = blockIdx.x;
    int j = threadIdx.x;              // 0..63, one truth per lane
    __shared__ int sp[O];
    int p = bp_idx[b * O + j];
    int v = bp_valid[b * O + j];
    sp[j] = p;
    float orig = bt_ov[b * P + p];    // pre-scatter value (depends only on p)
    __syncthreads();                  // all reads done before any write
    bool winner = true;
    for (int jj = j + 1; jj < O; ++jj)
        if (sp[jj] == p) { winner = false; break; }
    if (winner) {                     // winner == last j writing this p
        bt_ov[b * P + p] = v ? 2.0f : orig;
        bt_idx[b * P + p] = j;        // unconditional, even for invalid truths
    }
    unsigned long long av = __ballot(v != 0);
    if (j == 0) any_valid[b] = (av != 0ULL) ? 1 : 0;
}

// ---------------- Kernel D: per-prior losses + CE + rank score + coarse rank histogram
__global__ void kD_main(const float* __restrict__ loc_data, const float* __restrict__ conf_data,
                        const float* __restrict__ landm_data, const float* __restrict__ priors,
                        const float* __restrict__ targets,
                        const float* __restrict__ bt_ov, const int* __restrict__ bt_idx,
                        const int* __restrict__ any_valid,
                        float* __restrict__ rank, int* __restrict__ hist,
                        int* __restrict__ num_pos, float* __restrict__ pos_ce,
                        float* __restrict__ gsum, int* __restrict__ num_pos1_tot) {
    int chunk = blockIdx.x % NCHUNK;
    int b = blockIdx.x / NCHUNK;
    __shared__ float tg[O * 15];
    __shared__ float sredf[256];
    __shared__ int sredi[256];
    for (int i = threadIdx.x; i < O * 15; i += blockDim.x) tg[i] = targets[b * O * 15 + i];
    __syncthreads();
    int p = chunk * 256 + threadIdx.x;
    float ll = 0.f, llm = 0.f, cep = 0.f;
    int cp = 0, cp1 = 0;
    if (p < P) {
        float ov = bt_ov[b * P + p];
        int ti = bt_idx[b * P + p];
        int conf = 0;
        if (any_valid[b] && ov >= THRESH) conf = (int)tg[ti * 15 + 14];   // label is +-1.0 exactly
        float2 c01 = ((const float2*)conf_data)[b * P + p];
        float c0 = c01.x, c1 = c01.y;
        float m = fmaxf(c0, c1);
        float lse = m + logf(expf(c0 - m) + expf(c1 - m));
        bool pos = conf != 0;
        float ce = lse - (pos ? c1 : c0);
        float rv = pos ? 0.f : ce;
        rank[b * P + p] = rv;
        atomicAdd(&hist[b * HB + (__float_as_uint(rv) >> HSHIFT)], 1);
        if (pos) {
            cp = 1; cep = ce;
            float4 pr = ((const float4*)priors)[p];
            float cx = pr.x, cy = pr.y, sw = pr.z, sh = pr.w;
            const float* t = &tg[ti * 15];
            float gx = ((t[0] + t[2]) * 0.5f - cx) / (0.1f * sw);
            float gy = ((t[1] + t[3]) * 0.5f - cy) / (0.1f * sh);
            float gw = logf((t[2] - t[0]) / sw) / 0.2f;
            float gh = logf((t[3] - t[1]) / sh) / 0.2f;
            const float* ld = &loc_data[(size_t)(b * P + p) * 4];
            ll = smooth_l1(ld[0] - gx) + smooth_l1(ld[1] - gy) +
                 smooth_l1(ld[2] - gw) + smooth_l1(ld[3] - gh);
            if (conf > 0) {
                cp1 = 1;
                const float* lmd = &landm_data[(size_t)(b * P + p) * 10];
                for (int k5 = 0; k5 < 5; ++k5) {
                    float lx = (t[4 + k5 * 2 + 0] - cx) / (0.1f * sw);
                    float ly = (t[4 + k5 * 2 + 1] - cy) / (0.1f * sh);
                    llm += smooth_l1(lmd[k5 * 2 + 0] - lx) + smooth_l1(lmd[k5 * 2 + 1] - ly);
                }
            }
        }
    }
    sredf[threadIdx.x] = ll; __syncthreads();
    for (int s = 128; s > 0; s >>= 1) { if (threadIdx.x < s) sredf[threadIdx.x] += sredf[threadIdx.x + s]; __syncthreads(); }
    float ll_t = sredf[0]; __syncthreads();
    sredf[threadIdx.x] = llm; __syncthreads();
    for (int s = 128; s > 0; s >>= 1) { if (threadIdx.x < s) sredf[threadIdx.x] += sredf[threadIdx.x + s]; __syncthreads(); }
    float llm_t = sredf[0]; __syncthreads();
    sredf[threadIdx.x] = cep; __syncthreads();
    for (int s = 128; s > 0; s >>= 1) { if (threadIdx.x < s) sredf[threadIdx.x] += sredf[threadIdx.x + s]; __syncthreads(); }
    float cep_t = sredf[0]; __syncthreads();
    sredi[threadIdx.x] = cp; __syncthreads();
    for (int s = 128; s > 0; s >>= 1) { if (threadIdx.x < s) sredi[threadIdx.x] += sredi[threadIdx.x + s]; __syncthreads(); }
    int cp_t = sredi[0]; __syncthreads();
    sredi[threadIdx.x] = cp1; __syncthreads();
    for (int s = 128; s > 0; s >>= 1) { if (threadIdx.x < s) sredi[threadIdx.x] += sredi[threadIdx.x + s]; __syncthreads(); }
    int cp1_t = sredi[0];
    if (threadIdx.x == 0) {
        if (ll_t != 0.f)  atomicAdd(&gsum[0], ll_t);
        if (llm_t != 0.f) atomicAdd(&gsum[1], llm_t);
        if (cep_t != 0.f) atomicAdd(&pos_ce[b], cep_t);
        if (cp_t)  atomicAdd(&num_pos[b], cp_t);
        if (cp1_t) atomicAdd(num_pos1_tot, cp1_t);
    }
}

// ---------------- Kernel E: sum of top-k via precomputed coarse hist + ONE row pass.
// Candidates sharing the selected 12-bit prefix are gathered to LDS (typ. ~100-600)
// and the remaining 20 bits resolved there; global fallback if > CAP (pathological).
__global__ void kE_topk(const float* __restrict__ rank, const int* __restrict__ hist,
                        const int* __restrict__ num_pos, float* __restrict__ topk) {
    int b = blockIdx.x;
    const float* r = rank + (size_t)b * P;
    const int* h = hist + (size_t)b * HB;
    int k = num_pos[b] * 7;
    if (k > P - 1) k = P - 1;
    if (k <= 0) return;                 // topk pre-zeroed by memset
    __shared__ int chunkSum[256];
    __shared__ int s_bin, s_kk, s_cand_n;
    __shared__ unsigned cand[CAP];
    __shared__ int hist2[256];
    __shared__ float redf[256];
    __shared__ int redi[256];
    int t = threadIdx.x;
    // 1) locate coarse bin from hist (16 bins/thread, then serial top-down scan)
    int cs = 0;
#pragma unroll
    for (int i = 0; i < HB / 256; ++i) cs += h[t * (HB / 256) + i];
    chunkSum[t] = cs;
    __syncthreads();
    if (t == 0) {
        int cum = 0, bin = 0, kk = k;
        for (int c = 255; c >= 0; --c) {
            if (cum + chunkSum[c] >= k) {
                for (int i = HB / 256 - 1; i >= 0; --i) {
                    int hv = h[c * (HB / 256) + i];
                    if (cum + hv >= k) { bin = c * (HB / 256) + i; kk = k - cum; goto found; }
                    cum += hv;
                }
            }
            cum += chunkSum[c];
        }
    found:
        s_bin = bin; s_kk = kk; s_cand_n = 0;
    }
    __syncthreads();
    int bin = s_bin;
    int kk0 = s_kk;                      // rank needed within the bin; cnt_gt_row = k - kk0
    unsigned lo_bound = ((unsigned)(bin + 1)) << HSHIFT;   // u >= lo_bound <=> coarse bin > bin
    // 2) single row pass: sum of strictly-above-bin values + candidate gather
    float sumgt = 0.f;
    for (int p = t; p < P; p += 256) {
        float v = r[p];
        unsigned u = __float_as_uint(v);
        if (u >= lo_bound) sumgt += v;
        else if ((u >> HSHIFT) == (unsigned)bin) {
            int idx = atomicAdd(&s_cand_n, 1);
            if (idx < CAP) cand[idx] = u;
        }
    }
    redf[t] = sumgt; __syncthreads();
    for (int s = 128; s > 0; s >>= 1) { if (t < s) redf[t] += redf[t + s]; __syncthreads(); }
    float sum_gt_row = redf[0];
    __syncthreads();
    int m = s_cand_n;
    bool useLds = (m <= CAP);
    // 3) resolve remaining 20 bits: 8 + 8 + 4
    unsigned pref = ((unsigned)bin) << HSHIFT;
    unsigned resolved = 0xFFFFFFFFu << HSHIFT;
    int kk = kk0;
    const int shifts[3] = {12, 4, 0};
    const int nbins[3] = {256, 256, 16};
    for (int pass = 0; pass < 3; ++pass) {
        int sh = shifts[pass], nb = nbins[pass];
        for (int i = t; i < nb; i += 256) hist2[i] = 0;
        __syncthreads();
        if (useLds) {
            for (int i = t; i < m; i += 256) {
                unsigned u = cand[i];
                if ((u & resolved) == pref) atomicAdd(&hist2[(u >> sh) & (nb - 1)], 1);
            }
        } else {
            for (int p = t; p < P; p += 256) {
                unsigned u = __float_as_uint(r[p]);
                if ((u & resolved) == pref) atomicAdd(&hist2[(u >> sh) & (nb - 1)], 1);
            }
        }
        __syncthreads();
        if (t == 0) {
            int cum = 0, d = 0, kn = kk;
            for (int i = nb - 1; i >= 0; --i) {
                if (cum + hist2[i] >= kk) { d = i; kn = kk - cum; break; }
                cum += hist2[i];
            }
            s_bin = d; s_kk = kn;
        }
        __syncthreads();
        pref |= ((unsigned)s_bin) << sh;
        resolved |= (unsigned)(nb - 1) << sh;
        kk = s_kk;
        __syncthreads();
    }
    float tv = __uint_as_float(pref);    // exact k-th largest value
    // 4) sum/count of candidates strictly above t
    float sumS = 0.f; int cntS = 0;
    if (useLds) {
        for (int i = t; i < m; i += 256) {
            float v = __uint_as_float(cand[i]);
            if (v > tv) { sumS += v; cntS++; }
        }
    } else {
        for (int p = t; p < P; p += 256) {
            unsigned u = __float_as_uint(r[p]);
            if ((u >> HSHIFT) == (unsigned)bin) {
                float v = __uint_as_float(u);
                if (v > tv) { sumS += v; cntS++; }
            }
        }
    }
    redf[t] = sumS; redi[t] = cntS; __syncthreads();
    for (int s = 128; s > 0; s >>= 1) {
        if (t < s) { redf[t] += redf[t + s]; redi[t] += redi[t + s]; }
        __syncthreads();
    }
    if (t == 0) topk[b] = sum_gt_row + redf[0] + (float)(kk0 - redi[0]) * tv;
}

// ---------------- Kernel F: finalize
__global__ void kF_final(const int* __restrict__ num_pos, const float* __restrict__ pos_ce,
                         const float* __restrict__ topk, const float* __restrict__ gsum,
                         const int* __restrict__ num_pos1_tot, float* __restrict__ out) {
    if (threadIdx.x != 0 || blockIdx.x != 0) return;
    int np = 0; float lc = 0.f;
    for (int b = 0; b < B; ++b) { np += num_pos[b]; lc += pos_ce[b] + topk[b]; }
    float N = fmaxf((float)np, 1.f);
    float N1 = fmaxf((float)(*num_pos1_tot), 1.f);
    out[0] = gsum[0] / N;
    out[1] = lc / N;
    out[2] = gsum[1] / N1;
}

extern "C" void kernel_launch(void* const* d_in, const int* in_sizes, int n_in,
                              void* d_out, int out_size, void* d_ws, size_t ws_size,
                              hipStream_t stream) {
    const float* loc_data   = (const float*)d_in[0];
    const float* conf_data  = (const float*)d_in[1];
    const float* landm_data = (const float*)d_in[2];
    const float* priors     = (const float*)d_in[3];
    const float* targets    = (const float*)d_in[4];
    float* out = (float*)d_out;

    char* ws = (char*)d_ws;
    size_t off = 0;
    auto alloc = [&](size_t bytes) -> void* {
        void* p = ws + off;
        off += (bytes + 255) & ~(size_t)255;
        return p;
    };
    float* bt_ov    = (float*)alloc((size_t)B * P * 4);
    int*   bt_idx   = (int*)  alloc((size_t)B * P * 4);
    float* rank     = (float*)alloc((size_t)B * P * 4);
    int*   bp_idx   = (int*)  alloc(B * O * 4);
    int*   bp_valid = (int*)  alloc(B * O * 4);
    // hist + accumulators contiguous -> single memset
    size_t hist_bytes = (size_t)B * HB * 4;
    int*   hist = (int*)alloc(hist_bytes);
    size_t acc_bytes = (size_t)(B * 4 * 4 + 16);
    char* acc = (char*)alloc(acc_bytes);
    int*   any_valid    = (int*)acc;
    int*   num_pos      = (int*)(acc + B * 4);
    float* pos_ce       = (float*)(acc + 2 * B * 4);
    float* topk         = (float*)(acc + 3 * B * 4);
    float* gsum         = (float*)(acc + 4 * B * 4);
    int*   num_pos1_tot = (int*)(acc + 4 * B * 4 + 8);

    hipMemsetAsync(hist, 0, hist_bytes + 256 /*align pad*/ + acc_bytes, stream);

    kA_best_truth<<<dim3(B * NCHUNK), dim3(256), 0, stream>>>(priors, targets, bt_ov, bt_idx);
    kB_best_prior<<<dim3(B * (O / TG)), dim3(256), 0, stream>>>(priors, targets, bp_idx, bp_valid);
    kC_scatter<<<dim3(B), dim3(64), 0, stream>>>(bp_idx, bp_valid, bt_ov, bt_idx, any_valid);
    kD_main<<<dim3(B * NCHUNK), dim3(256), 0, stream>>>(loc_data, conf_data, landm_data, priors,
                                                        targets, bt_ov, bt_idx, any_valid, rank,
                                                        hist, num_pos, pos_ce, gsum, num_pos1_tot);
    kE_topk<<<dim3(B), dim3(256), 0, stream>>>(rank, hist, num_pos, topk);
    kF_final<<<dim3(1), dim3(64), 0, stream>>>(num_pos, pos_ce, topk, gsum, num_pos1_tot, out);
}

// Round 3
// 342.688 us; speedup vs baseline: 1.1279x; 1.1279x over previous
//
#include <hip/hip_runtime.h>
#include <math.h>

#define B 64
#define P 16800
#define O 64
#define NCHUNK 66          // ceil(16800/256)
#define THRESH 0.35f
#define VALID_T 0.2f
#define HB 4096            // coarse hist bins = top 12 bits of float bits (rank >= 0)
#define HSHIFT 20
#define CAP 4096           // candidate buffer capacity in kE
#define TG 8               // truths per kB block

__device__ __forceinline__ float smooth_l1(float x) {
    float ax = fabsf(x);
    return ax < 1.f ? 0.5f * ax * ax : ax - 0.5f;
}

__device__ __forceinline__ float wave_sum(float v) {
#pragma unroll
    for (int s = 32; s > 0; s >>= 1) v += __shfl_down(v, s, 64);
    return v;
}
__device__ __forceinline__ int wave_sum_i(int v) {
#pragma unroll
    for (int s = 32; s > 0; s >>= 1) v += __shfl_down(v, s, 64);
    return v;
}

// ---------------- Kernel A: per-prior best truth (argmax over O, first-max tie-break)
__global__ void kA_best_truth(const float* __restrict__ priors,
                              const float* __restrict__ targets,
                              float* __restrict__ bt_ov, int* __restrict__ bt_idx) {
    int chunk = blockIdx.x % NCHUNK;
    int b = blockIdx.x / NCHUNK;
    __shared__ float tg[O * 15];
    for (int i = threadIdx.x; i < O * 15; i += blockDim.x) tg[i] = targets[b * O * 15 + i];
    __syncthreads();
    int p = chunk * 256 + threadIdx.x;
    if (p >= P) return;
    float4 pr = ((const float4*)priors)[p];
    float px1 = pr.x - pr.z * 0.5f, py1 = pr.y - pr.w * 0.5f;
    float px2 = pr.x + pr.z * 0.5f, py2 = pr.y + pr.w * 0.5f;
    float area_b = (px2 - px1) * (py2 - py1);
    float best = -1.f; int bi = 0;
    for (int o = 0; o < O; ++o) {
        const float* t = &tg[o * 15];
        float w = fmaxf(fminf(t[2], px2) - fmaxf(t[0], px1), 0.f);
        float h = fmaxf(fminf(t[3], py2) - fmaxf(t[1], py1), 0.f);
        float inter = w * h;
        float area_a = (t[2] - t[0]) * (t[3] - t[1]);
        float iou = inter / (area_a + area_b - inter);
        if (iou > best) { best = iou; bi = o; }   // strict >: first max wins (jnp.argmax)
    }
    bt_ov[b * P + p] = best;
    bt_idx[b * P + p] = bi;
}

// ---------------- Kernel B: per-truth best prior. Grid B x (O/TG); each block covers
// the ENTIRE prior range for TG truths.
__global__ void kB_best_prior(const float* __restrict__ priors,
                              const float* __restrict__ targets,
                              int* __restrict__ bp_idx, int* __restrict__ bp_valid) {
    int g = blockIdx.x % (O / TG);
    int b = blockIdx.x / (O / TG);
    __shared__ float tb[TG][5];   // x1,y1,x2,y2,area
    if (threadIdx.x < TG * 5) {
        int o = threadIdx.x / 5, c = threadIdx.x % 5;
        const float* t = &targets[(b * O + g * TG + o) * 15];
        tb[o][c] = (c < 4) ? t[c] : (t[2] - t[0]) * (t[3] - t[1]);
    }
    __syncthreads();
    unsigned long long key[TG];
#pragma unroll
    for (int o = 0; o < TG; ++o) key[o] = 0ULL;
    for (int p = threadIdx.x; p < P; p += 256) {
        float4 pr = ((const float4*)priors)[p];
        float px1 = pr.x - pr.z * 0.5f, py1 = pr.y - pr.w * 0.5f;
        float px2 = pr.x + pr.z * 0.5f, py2 = pr.y + pr.w * 0.5f;
        float area_b = (px2 - px1) * (py2 - py1);
        unsigned pkey = 0xFFFFFFFFu - (unsigned)p;   // ties -> smaller p wins
#pragma unroll
        for (int o = 0; o < TG; ++o) {
            float w = fmaxf(fminf(tb[o][2], px2) - fmaxf(tb[o][0], px1), 0.f);
            float h = fmaxf(fminf(tb[o][3], py2) - fmaxf(tb[o][1], py1), 0.f);
            float inter = w * h;
            float iou = inter / (tb[o][4] + area_b - inter);
            unsigned long long kk = ((unsigned long long)__float_as_uint(iou) << 32) | pkey;
            if (kk > key[o]) key[o] = kk;
        }
    }
    __shared__ unsigned long long red[256];
    for (int o = 0; o < TG; ++o) {
        red[threadIdx.x] = key[o];
        __syncthreads();
        for (int s = 128; s > 0; s >>= 1) {
            if (threadIdx.x < s) {
                unsigned long long a = red[threadIdx.x], c = red[threadIdx.x + s];
                red[threadIdx.x] = a > c ? a : c;
            }
            __syncthreads();
        }
        if (threadIdx.x == 0) {
            unsigned long long kk = red[0];
            int pp = (int)(0xFFFFFFFFu - (unsigned)(kk & 0xFFFFFFFFu));
            float iou = __uint_as_float((unsigned)(kk >> 32));
            bp_idx[b * O + g * TG + o] = pp;
            bp_valid[b * O + g * TG + o] = (iou >= VALID_T) ? 1 : 0;
        }
        __syncthreads();
    }
}

// ---------------- Kernel C: scatter overrides, one wave per row.
__global__ void kC_scatter(const int* __restrict__ bp_idx, const int* __restrict__ bp_valid,
                           float* __restrict__ bt_ov, int* __restrict__ bt_idx,
                           int* __restrict__ any_valid) {
    int b = blockIdx.x;
    int j = threadIdx.x;              // 0..63, one truth per lane
    __shared__ int sp[O];
    int p = bp_idx[b * O + j];
    int v = bp_valid[b * O + j];
    sp[j] = p;
    float orig = bt_ov[b * P + p];    // pre-scatter value (depends only on p)
    __syncthreads();                  // all reads done before any write
    bool winner = true;
    for (int jj = j + 1; jj < O; ++jj)
        if (sp[jj] == p) { winner = false; break; }
    if (winner) {                     // winner == last j writing this p
        bt_ov[b * P + p] = v ? 2.0f : orig;
        bt_idx[b * P + p] = j;        // unconditional, even for invalid truths
    }
    unsigned long long av = __ballot(v != 0);
    if (j == 0) any_valid[b] = (av != 0ULL) ? 1 : 0;
}

// ---------------- Kernel D: per-prior losses + CE + rank score + coarse rank histogram.
// Histogram is aggregated in LDS per block, then flushed with one global atomic per
// NONZERO bin (Guideline 12: aggregate before global atomics).
__global__ void kD_main(const float* __restrict__ loc_data, const float* __restrict__ conf_data,
                        const float* __restrict__ landm_data, const float* __restrict__ priors,
                        const float* __restrict__ targets,
                        const float* __restrict__ bt_ov, const int* __restrict__ bt_idx,
                        const int* __restrict__ any_valid,
                        float* __restrict__ rank, int* __restrict__ hist,
                        int* __restrict__ num_pos, float* __restrict__ pos_ce,
                        float* __restrict__ gsum, int* __restrict__ num_pos1_tot) {
    int chunk = blockIdx.x % NCHUNK;
    int b = blockIdx.x / NCHUNK;
    __shared__ float tg[O * 15];
    __shared__ int lhist[HB];
    __shared__ float wredf[3][4];
    __shared__ int wredi[2][4];
    for (int i = threadIdx.x; i < O * 15; i += blockDim.x) tg[i] = targets[b * O * 15 + i];
    for (int i = threadIdx.x; i < HB; i += blockDim.x) lhist[i] = 0;
    __syncthreads();
    int p = chunk * 256 + threadIdx.x;
    float ll = 0.f, llm = 0.f, cep = 0.f;
    int cp = 0, cp1 = 0;
    if (p < P) {
        float ov = bt_ov[b * P + p];
        int ti = bt_idx[b * P + p];
        int conf = 0;
        if (any_valid[b] && ov >= THRESH) conf = (int)tg[ti * 15 + 14];   // label is +-1.0 exactly
        float2 c01 = ((const float2*)conf_data)[b * P + p];
        float c0 = c01.x, c1 = c01.y;
        float m = fmaxf(c0, c1);
        float lse = m + logf(expf(c0 - m) + expf(c1 - m));
        bool pos = conf != 0;
        float ce = lse - (pos ? c1 : c0);
        float rv = pos ? 0.f : ce;
        rank[b * P + p] = rv;
        atomicAdd(&lhist[__float_as_uint(rv) >> HSHIFT], 1);
        if (pos) {
            cp = 1; cep = ce;
            float4 pr = ((const float4*)priors)[p];
            float cx = pr.x, cy = pr.y, sw = pr.z, sh = pr.w;
            const float* t = &tg[ti * 15];
            float gx = ((t[0] + t[2]) * 0.5f - cx) / (0.1f * sw);
            float gy = ((t[1] + t[3]) * 0.5f - cy) / (0.1f * sh);
            float gw = logf((t[2] - t[0]) / sw) / 0.2f;
            float gh = logf((t[3] - t[1]) / sh) / 0.2f;
            const float* ld = &loc_data[(size_t)(b * P + p) * 4];
            ll = smooth_l1(ld[0] - gx) + smooth_l1(ld[1] - gy) +
                 smooth_l1(ld[2] - gw) + smooth_l1(ld[3] - gh);
            if (conf > 0) {
                cp1 = 1;
                const float* lmd = &landm_data[(size_t)(b * P + p) * 10];
                for (int k5 = 0; k5 < 5; ++k5) {
                    float lx = (t[4 + k5 * 2 + 0] - cx) / (0.1f * sw);
                    float ly = (t[4 + k5 * 2 + 1] - cy) / (0.1f * sh);
                    llm += smooth_l1(lmd[k5 * 2 + 0] - lx) + smooth_l1(lmd[k5 * 2 + 1] - ly);
                }
            }
        }
    }
    // wave-level shuffle reductions, then cross-wave combine by thread 0
    int wid = threadIdx.x >> 6, lid = threadIdx.x & 63;
    float s_ll = wave_sum(ll), s_llm = wave_sum(llm), s_cep = wave_sum(cep);
    int s_cp = wave_sum_i(cp), s_cp1 = wave_sum_i(cp1);
    if (lid == 0) {
        wredf[0][wid] = s_ll; wredf[1][wid] = s_llm; wredf[2][wid] = s_cep;
        wredi[0][wid] = s_cp; wredi[1][wid] = s_cp1;
    }
    __syncthreads();
    if (threadIdx.x == 0) {
        float ll_t = wredf[0][0] + wredf[0][1] + wredf[0][2] + wredf[0][3];
        float llm_t = wredf[1][0] + wredf[1][1] + wredf[1][2] + wredf[1][3];
        float cep_t = wredf[2][0] + wredf[2][1] + wredf[2][2] + wredf[2][3];
        int cp_t = wredi[0][0] + wredi[0][1] + wredi[0][2] + wredi[0][3];
        int cp1_t = wredi[1][0] + wredi[1][1] + wredi[1][2] + wredi[1][3];
        if (ll_t != 0.f)  atomicAdd(&gsum[0], ll_t);
        if (llm_t != 0.f) atomicAdd(&gsum[1], llm_t);
        if (cep_t != 0.f) atomicAdd(&pos_ce[b], cep_t);
        if (cp_t)  atomicAdd(&num_pos[b], cp_t);
        if (cp1_t) atomicAdd(num_pos1_tot, cp1_t);
    }
    // flush nonzero LDS hist bins to global (<=256 distinct bins possible per block)
    int* gh = hist + (size_t)b * HB;
#pragma unroll
    for (int i = threadIdx.x; i < HB; i += 256) {
        int c = lhist[i];
        if (c) atomicAdd(&gh[i], c);
    }
}

// ---------------- Kernel E: sum of top-k via precomputed coarse hist + ONE row pass.
__global__ void kE_topk(const float* __restrict__ rank, const int* __restrict__ hist,
                        const int* __restrict__ num_pos, float* __restrict__ topk) {
    int b = blockIdx.x;
    const float* r = rank + (size_t)b * P;
    const int* h = hist + (size_t)b * HB;
    int k = num_pos[b] * 7;
    if (k > P - 1) k = P - 1;
    if (k <= 0) return;                 // topk pre-zeroed by memset
    __shared__ int chunkSum[256];
    __shared__ int s_bin, s_kk, s_cand_n;
    __shared__ unsigned cand[CAP];
    __shared__ int hist2[256];
    __shared__ float redf[256];
    __shared__ int redi[256];
    int t = threadIdx.x;
    int cs = 0;
#pragma unroll
    for (int i = 0; i < HB / 256; ++i) cs += h[t * (HB / 256) + i];
    chunkSum[t] = cs;
    __syncthreads();
    if (t == 0) {
        int cum = 0, bin = 0, kk = k;
        for (int c = 255; c >= 0; --c) {
            if (cum + chunkSum[c] >= k) {
                for (int i = HB / 256 - 1; i >= 0; --i) {
                    int hv = h[c * (HB / 256) + i];
                    if (cum + hv >= k) { bin = c * (HB / 256) + i; kk = k - cum; goto found; }
                    cum += hv;
                }
            }
            cum += chunkSum[c];
        }
    found:
        s_bin = bin; s_kk = kk; s_cand_n = 0;
    }
    __syncthreads();
    int bin = s_bin;
    int kk0 = s_kk;
    unsigned lo_bound = ((unsigned)(bin + 1)) << HSHIFT;
    float sumgt = 0.f;
    for (int p = t; p < P; p += 256) {
        float v = r[p];
        unsigned u = __float_as_uint(v);
        if (u >= lo_bound) sumgt += v;
        else if ((u >> HSHIFT) == (unsigned)bin) {
            int idx = atomicAdd(&s_cand_n, 1);
            if (idx < CAP) cand[idx] = u;
        }
    }
    redf[t] = sumgt; __syncthreads();
    for (int s = 128; s > 0; s >>= 1) { if (t < s) redf[t] += redf[t + s]; __syncthreads(); }
    float sum_gt_row = redf[0];
    __syncthreads();
    int m = s_cand_n;
    bool useLds = (m <= CAP);
    unsigned pref = ((unsigned)bin) << HSHIFT;
    unsigned resolved = 0xFFFFFFFFu << HSHIFT;
    int kk = kk0;
    const int shifts[3] = {12, 4, 0};
    const int nbins[3] = {256, 256, 16};
    for (int pass = 0; pass < 3; ++pass) {
        int sh = shifts[pass], nb = nbins[pass];
        for (int i = t; i < nb; i += 256) hist2[i] = 0;
        __syncthreads();
        if (useLds) {
            for (int i = t; i < m; i += 256) {
                unsigned u = cand[i];
                if ((u & resolved) == pref) atomicAdd(&hist2[(u >> sh) & (nb - 1)], 1);
            }
        } else {
            for (int p = t; p < P; p += 256) {
                unsigned u = __float_as_uint(r[p]);
                if ((u & resolved) == pref) atomicAdd(&hist2[(u >> sh) & (nb - 1)], 1);
            }
        }
        __syncthreads();
        if (t == 0) {
            int cum = 0, d = 0, kn = kk;
            for (int i = nb - 1; i >= 0; --i) {
                if (cum + hist2[i] >= kk) { d = i; kn = kk - cum; break; }
                cum += hist2[i];
            }
            s_bin = d; s_kk = kn;
        }
        __syncthreads();
        pref |= ((unsigned)s_bin) << sh;
        resolved |= (unsigned)(nb - 1) << sh;
        kk = s_kk;
        __syncthreads();
    }
    float tv = __uint_as_float(pref);    // exact k-th largest value
    float sumS = 0.f; int cntS = 0;
    if (useLds) {
        for (int i = t; i < m; i += 256) {
            float v = __uint_as_float(cand[i]);
            if (v > tv) { sumS += v; cntS++; }
        }
    } else {
        for (int p = t; p < P; p += 256) {
            unsigned u = __float_as_uint(r[p]);
            if ((u >> HSHIFT) == (unsigned)bin) {
                float v = __uint_as_float(u);
                if (v > tv) { sumS += v; cntS++; }
            }
        }
    }
    redf[t] = sumS; redi[t] = cntS; __syncthreads();
    for (int s = 128; s > 0; s >>= 1) {
        if (t < s) { redf[t] += redf[t + s]; redi[t] += redi[t + s]; }
        __syncthreads();
    }
    if (t == 0) topk[b] = sum_gt_row + redf[0] + (float)(kk0 - redi[0]) * tv;
}

// ---------------- Kernel F: finalize
__global__ void kF_final(const int* __restrict__ num_pos, const float* __restrict__ pos_ce,
                         const float* __restrict__ topk, const float* __restrict__ gsum,
                         const int* __restrict__ num_pos1_tot, float* __restrict__ out) {
    if (threadIdx.x != 0 || blockIdx.x != 0) return;
    int np = 0; float lc = 0.f;
    for (int b = 0; b < B; ++b) { np += num_pos[b]; lc += pos_ce[b] + topk[b]; }
    float N = fmaxf((float)np, 1.f);
    float N1 = fmaxf((float)(*num_pos1_tot), 1.f);
    out[0] = gsum[0] / N;
    out[1] = lc / N;
    out[2] = gsum[1] / N1;
}

extern "C" void kernel_launch(void* const* d_in, const int* in_sizes, int n_in,
                              void* d_out, int out_size, void* d_ws, size_t ws_size,
                              hipStream_t stream) {
    const float* loc_data   = (const float*)d_in[0];
    const float* conf_data  = (const float*)d_in[1];
    const float* landm_data = (const float*)d_in[2];
    const float* priors     = (const float*)d_in[3];
    const float* targets    = (const float*)d_in[4];
    float* out = (float*)d_out;

    char* ws = (char*)d_ws;
    size_t off = 0;
    auto alloc = [&](size_t bytes) -> void* {
        void* p = ws + off;
        off += (bytes + 255) & ~(size_t)255;
        return p;
    };
    float* bt_ov    = (float*)alloc((size_t)B * P * 4);
    int*   bt_idx   = (int*)  alloc((size_t)B * P * 4);
    float* rank     = (float*)alloc((size_t)B * P * 4);
    int*   bp_idx   = (int*)  alloc(B * O * 4);
    int*   bp_valid = (int*)  alloc(B * O * 4);
    size_t hist_bytes = (size_t)B * HB * 4;
    int*   hist = (int*)alloc(hist_bytes);
    size_t acc_bytes = (size_t)(B * 4 * 4 + 16);
    char* acc = (char*)alloc(acc_bytes);
    int*   any_valid    = (int*)acc;
    int*   num_pos      = (int*)(acc + B * 4);
    float* pos_ce       = (float*)(acc + 2 * B * 4);
    float* topk         = (float*)(acc + 3 * B * 4);
    float* gsum         = (float*)(acc + 4 * B * 4);
    int*   num_pos1_tot = (int*)(acc + 4 * B * 4 + 8);

    hipMemsetAsync(hist, 0, hist_bytes + 256 /*align pad*/ + acc_bytes, stream);

    kA_best_truth<<<dim3(B * NCHUNK), dim3(256), 0, stream>>>(priors, targets, bt_ov, bt_idx);
    kB_best_prior<<<dim3(B * (O / TG)), dim3(256), 0, stream>>>(priors, targets, bp_idx, bp_valid);
    kC_scatter<<<dim3(B), dim3(64), 0, stream>>>(bp_idx, bp_valid, bt_ov, bt_idx, any_valid);
    kD_main<<<dim3(B * NCHUNK), dim3(256), 0, stream>>>(loc_data, conf_data, landm_data, priors,
                                                        targets, bt_ov, bt_idx, any_valid, rank,
                                                        hist, num_pos, pos_ce, gsum, num_pos1_tot);
    kE_topk<<<dim3(B), dim3(256), 0, stream>>>(rank, hist, num_pos, topk);
    kF_final<<<dim3(1), dim3(64), 0, stream>>>(num_pos, pos_ce, topk, gsum, num_pos1_tot, out);
}

// Round 4
// 297.616 us; speedup vs baseline: 1.2988x; 1.1514x over previous
//
#include <hip/hip_runtime.h>
#include <math.h>

#define B 64
#define P 16800
#define O 64
#define NCHUNK 66          // ceil(16800/256)
#define THRESH 0.35f
#define VALID_T 0.2f
#define HB 4096            // coarse hist bins = top 12 bits of float bits (rank >= 0)
#define HSHIFT 20
#define CAP 4096           // candidate buffer capacity in kE
#define TG 8               // truths per kB block
#define SPLIT 4            // prior-range splits in kB
#define PCH (P / SPLIT)    // 4200

__device__ __forceinline__ float smooth_l1(float x) {
    float ax = fabsf(x);
    return ax < 1.f ? 0.5f * ax * ax : ax - 0.5f;
}

__device__ __forceinline__ float wave_sum(float v) {
#pragma unroll
    for (int s = 32; s > 0; s >>= 1) v += __shfl_down(v, s, 64);
    return v;
}
__device__ __forceinline__ int wave_sum_i(int v) {
#pragma unroll
    for (int s = 32; s > 0; s >>= 1) v += __shfl_down(v, s, 64);
    return v;
}

// ---------------- Kernel A: per-prior best truth (argmax over O, first-max tie-break).
// Zero-intersection truths can never win (iou=0, best init 0, strict >), so the
// divide is wave-skipped when no lane overlaps truth o.
__global__ void kA_best_truth(const float* __restrict__ priors,
                              const float* __restrict__ targets,
                              float* __restrict__ bt_ov, int* __restrict__ bt_idx) {
    int chunk = blockIdx.x % NCHUNK;
    int b = blockIdx.x / NCHUNK;
    __shared__ float tx1[O], ty1[O], tx2[O], ty2[O], ta[O];
    if (threadIdx.x < O) {
        const float* t = &targets[(b * O + threadIdx.x) * 15];
        float a0 = t[0], a1 = t[1], a2 = t[2], a3 = t[3];
        tx1[threadIdx.x] = a0; ty1[threadIdx.x] = a1;
        tx2[threadIdx.x] = a2; ty2[threadIdx.x] = a3;
        ta[threadIdx.x] = (a2 - a0) * (a3 - a1);
    }
    __syncthreads();
    int p = chunk * 256 + threadIdx.x;
    if (p >= P) return;
    float4 pr = ((const float4*)priors)[p];
    float px1 = pr.x - pr.z * 0.5f, py1 = pr.y - pr.w * 0.5f;
    float px2 = pr.x + pr.z * 0.5f, py2 = pr.y + pr.w * 0.5f;
    float area_b = (px2 - px1) * (py2 - py1);
    float best = 0.f; int bi = 0;    // all-zero row -> argmax = 0, ov = 0 (matches ref)
    for (int o = 0; o < O; ++o) {
        float w = fmaxf(fminf(tx2[o], px2) - fmaxf(tx1[o], px1), 0.f);
        float h = fmaxf(fminf(ty2[o], py2) - fmaxf(ty1[o], py1), 0.f);
        float inter = w * h;
        if (__any(inter > 0.f)) {
            float iou = inter / (ta[o] + area_b - inter);
            if (iou > best) { best = iou; bi = o; }   // strict >: first max wins
        }
    }
    bt_ov[b * P + p] = best;
    bt_idx[b * P + p] = bi;
}

// ---------------- Kernel B: per-truth best prior, partial over a P-split.
// Truths live in REGISTERS (not LDS); float compare in-loop, u64 pack only at the
// reduction; zero-intersection wave-skip. Output: u64 key per (b,o,split).
__global__ void __launch_bounds__(256) kB_best_prior(
        const float* __restrict__ priors, const float* __restrict__ targets,
        unsigned long long* __restrict__ bp_part) {
    int s = blockIdx.x % SPLIT;
    int g = (blockIdx.x / SPLIT) % (O / TG);
    int b = blockIdx.x / (SPLIT * (O / TG));
    float tx1[TG], ty1[TG], tx2[TG], ty2[TG], ta[TG];
#pragma unroll
    for (int o = 0; o < TG; ++o) {
        const float* t = &targets[(b * O + g * TG + o) * 15];
        tx1[o] = t[0]; ty1[o] = t[1]; tx2[o] = t[2]; ty2[o] = t[3];
        ta[o] = (tx2[o] - tx1[o]) * (ty2[o] - ty1[o]);
    }
    int p0 = s * PCH;
    float best[TG]; int bp[TG];
#pragma unroll
    for (int o = 0; o < TG; ++o) { best[o] = 0.f; bp[o] = p0 + (int)threadIdx.x; }
    for (int p = p0 + (int)threadIdx.x; p < p0 + PCH; p += 256) {
        float4 pr = ((const float4*)priors)[p];
        float px1 = pr.x - pr.z * 0.5f, py1 = pr.y - pr.w * 0.5f;
        float px2 = pr.x + pr.z * 0.5f, py2 = pr.y + pr.w * 0.5f;
        float area_b = (px2 - px1) * (py2 - py1);
#pragma unroll
        for (int o = 0; o < TG; ++o) {
            float w = fmaxf(fminf(tx2[o], px2) - fmaxf(tx1[o], px1), 0.f);
            float h = fmaxf(fminf(ty2[o], py2) - fmaxf(ty1[o], py1), 0.f);
            float inter = w * h;
            if (__any(inter > 0.f)) {
                float iou = inter / (ta[o] + area_b - inter);
                if (iou > best[o]) { best[o] = iou; bp[o] = p; }  // ascending p: first max
            }
        }
    }
    // pack + wave reduce + cross-wave reduce
    __shared__ unsigned long long wk[4][TG];
    int wid = threadIdx.x >> 6, lid = threadIdx.x & 63;
#pragma unroll
    for (int o = 0; o < TG; ++o) {
        unsigned long long key = ((unsigned long long)__float_as_uint(best[o]) << 32)
                               | (unsigned)(0xFFFFFFFFu - (unsigned)bp[o]);
#pragma unroll
        for (int sft = 32; sft > 0; sft >>= 1) {
            unsigned long long other = __shfl_down(key, sft, 64);
            if (other > key) key = other;
        }
        if (lid == 0) wk[wid][o] = key;
    }
    __syncthreads();
    if (threadIdx.x < TG) {
        unsigned long long k0 = wk[0][threadIdx.x];
#pragma unroll
        for (int w = 1; w < 4; ++w) {
            unsigned long long kw = wk[w][threadIdx.x];
            if (kw > k0) k0 = kw;
        }
        bp_part[(size_t)(b * O + g * TG + threadIdx.x) * SPLIT + s] = k0;
    }
}

// ---------------- Kernel C: finish kB reduction + scatter overrides, one wave per row.
__global__ void kC_scatter(const unsigned long long* __restrict__ bp_part,
                           float* __restrict__ bt_ov, int* __restrict__ bt_idx,
                           int* __restrict__ any_valid) {
    int b = blockIdx.x;
    int j = threadIdx.x;              // 0..63, one truth per lane
    unsigned long long k = bp_part[(size_t)(b * O + j) * SPLIT];
#pragma unroll
    for (int s = 1; s < SPLIT; ++s) {
        unsigned long long kw = bp_part[(size_t)(b * O + j) * SPLIT + s];
        if (kw > k) k = kw;
    }
    int p = (int)(0xFFFFFFFFu - (unsigned)(k & 0xFFFFFFFFu));
    float iou = __uint_as_float((unsigned)(k >> 32));
    int v = (iou >= VALID_T) ? 1 : 0;
    __shared__ int sp[O];
    sp[j] = p;
    float orig = bt_ov[b * P + p];    // pre-scatter value (depends only on p)
    __syncthreads();                  // all reads done before any write
    bool winner = true;
    for (int jj = j + 1; jj < O; ++jj)
        if (sp[jj] == p) { winner = false; break; }
    if (winner) {                     // winner == last j writing this p (numpy semantics)
        bt_ov[b * P + p] = v ? 2.0f : orig;
        bt_idx[b * P + p] = j;        // unconditional, even for invalid truths
    }
    unsigned long long av = __ballot(v != 0);
    if (j == 0) any_valid[b] = (av != 0ULL) ? 1 : 0;
}

// ---------------- Kernel D: per-prior losses + CE + rank score + coarse rank histogram.
// Histogram aggregated in LDS, flushed once per nonzero bin.
__global__ void kD_main(const float* __restrict__ loc_data, const float* __restrict__ conf_data,
                        const float* __restrict__ landm_data, const float* __restrict__ priors,
                        const float* __restrict__ targets,
                        const float* __restrict__ bt_ov, const int* __restrict__ bt_idx,
                        const int* __restrict__ any_valid,
                        float* __restrict__ rank, int* __restrict__ hist,
                        int* __restrict__ num_pos, float* __restrict__ pos_ce,
                        float* __restrict__ gsum, int* __restrict__ num_pos1_tot) {
    int chunk = blockIdx.x % NCHUNK;
    int b = blockIdx.x / NCHUNK;
    __shared__ float tg[O * 15];
    __shared__ int lhist[HB];
    __shared__ float wredf[3][4];
    __shared__ int wredi[2][4];
    for (int i = threadIdx.x; i < O * 15; i += blockDim.x) tg[i] = targets[b * O * 15 + i];
    for (int i = threadIdx.x; i < HB; i += blockDim.x) lhist[i] = 0;
    __syncthreads();
    int p = chunk * 256 + threadIdx.x;
    float ll = 0.f, llm = 0.f, cep = 0.f;
    int cp = 0, cp1 = 0;
    if (p < P) {
        float ov = bt_ov[b * P + p];
        int ti = bt_idx[b * P + p];
        int conf = 0;
        if (any_valid[b] && ov >= THRESH) conf = (int)tg[ti * 15 + 14];   // label is +-1.0 exactly
        float2 c01 = ((const float2*)conf_data)[b * P + p];
        float c0 = c01.x, c1 = c01.y;
        float m = fmaxf(c0, c1);
        float lse = m + logf(expf(c0 - m) + expf(c1 - m));
        bool pos = conf != 0;
        float ce = lse - (pos ? c1 : c0);
        float rv = pos ? 0.f : ce;
        rank[b * P + p] = rv;
        atomicAdd(&lhist[__float_as_uint(rv) >> HSHIFT], 1);
        if (pos) {
            cp = 1; cep = ce;
            float4 pr = ((const float4*)priors)[p];
            float cx = pr.x, cy = pr.y, sw = pr.z, sh = pr.w;
            const float* t = &tg[ti * 15];
            float gx = ((t[0] + t[2]) * 0.5f - cx) / (0.1f * sw);
            float gy = ((t[1] + t[3]) * 0.5f - cy) / (0.1f * sh);
            float gw = logf((t[2] - t[0]) / sw) / 0.2f;
            float gh = logf((t[3] - t[1]) / sh) / 0.2f;
            const float* ld = &loc_data[(size_t)(b * P + p) * 4];
            ll = smooth_l1(ld[0] - gx) + smooth_l1(ld[1] - gy) +
                 smooth_l1(ld[2] - gw) + smooth_l1(ld[3] - gh);
            if (conf > 0) {
                cp1 = 1;
                const float* lmd = &landm_data[(size_t)(b * P + p) * 10];
                for (int k5 = 0; k5 < 5; ++k5) {
                    float lx = (t[4 + k5 * 2 + 0] - cx) / (0.1f * sw);
                    float ly = (t[4 + k5 * 2 + 1] - cy) / (0.1f * sh);
                    llm += smooth_l1(lmd[k5 * 2 + 0] - lx) + smooth_l1(lmd[k5 * 2 + 1] - ly);
                }
            }
        }
    }
    int wid = threadIdx.x >> 6, lid = threadIdx.x & 63;
    float s_ll = wave_sum(ll), s_llm = wave_sum(llm), s_cep = wave_sum(cep);
    int s_cp = wave_sum_i(cp), s_cp1 = wave_sum_i(cp1);
    if (lid == 0) {
        wredf[0][wid] = s_ll; wredf[1][wid] = s_llm; wredf[2][wid] = s_cep;
        wredi[0][wid] = s_cp; wredi[1][wid] = s_cp1;
    }
    __syncthreads();
    if (threadIdx.x == 0) {
        float ll_t = wredf[0][0] + wredf[0][1] + wredf[0][2] + wredf[0][3];
        float llm_t = wredf[1][0] + wredf[1][1] + wredf[1][2] + wredf[1][3];
        float cep_t = wredf[2][0] + wredf[2][1] + wredf[2][2] + wredf[2][3];
        int cp_t = wredi[0][0] + wredi[0][1] + wredi[0][2] + wredi[0][3];
        int cp1_t = wredi[1][0] + wredi[1][1] + wredi[1][2] + wredi[1][3];
        if (ll_t != 0.f)  atomicAdd(&gsum[0], ll_t);
        if (llm_t != 0.f) atomicAdd(&gsum[1], llm_t);
        if (cep_t != 0.f) atomicAdd(&pos_ce[b], cep_t);
        if (cp_t)  atomicAdd(&num_pos[b], cp_t);
        if (cp1_t) atomicAdd(num_pos1_tot, cp1_t);
    }
    int* gh = hist + (size_t)b * HB;
#pragma unroll
    for (int i = threadIdx.x; i < HB; i += 256) {
        int c = lhist[i];
        if (c) atomicAdd(&gh[i], c);
    }
}

// ---------------- Kernel E: sum of top-k via precomputed coarse hist + ONE row pass.
__global__ void kE_topk(const float* __restrict__ rank, const int* __restrict__ hist,
                        const int* __restrict__ num_pos, float* __restrict__ topk) {
    int b = blockIdx.x;
    const float* r = rank + (size_t)b * P;
    const int* h = hist + (size_t)b * HB;
    int k = num_pos[b] * 7;
    if (k > P - 1) k = P - 1;
    if (k <= 0) return;                 // topk pre-zeroed by memset
    __shared__ int chunkSum[256];
    __shared__ int s_bin, s_kk, s_cand_n;
    __shared__ unsigned cand[CAP];
    __shared__ int hist2[256];
    __shared__ float redf[256];
    __shared__ int redi[256];
    int t = threadIdx.x;
    int cs = 0;
#pragma unroll
    for (int i = 0; i < HB / 256; ++i) cs += h[t * (HB / 256) + i];
    chunkSum[t] = cs;
    __syncthreads();
    if (t == 0) {
        int cum = 0, bin = 0, kk = k;
        for (int c = 255; c >= 0; --c) {
            if (cum + chunkSum[c] >= k) {
                for (int i = HB / 256 - 1; i >= 0; --i) {
                    int hv = h[c * (HB / 256) + i];
                    if (cum + hv >= k) { bin = c * (HB / 256) + i; kk = k - cum; goto found; }
                    cum += hv;
                }
            }
            cum += chunkSum[c];
        }
    found:
        s_bin = bin; s_kk = kk; s_cand_n = 0;
    }
    __syncthreads();
    int bin = s_bin;
    int kk0 = s_kk;
    unsigned lo_bound = ((unsigned)(bin + 1)) << HSHIFT;
    float sumgt = 0.f;
    for (int p = t; p < P; p += 256) {
        float v = r[p];
        unsigned u = __float_as_uint(v);
        if (u >= lo_bound) sumgt += v;
        else if ((u >> HSHIFT) == (unsigned)bin) {
            int idx = atomicAdd(&s_cand_n, 1);
            if (idx < CAP) cand[idx] = u;
        }
    }
    redf[t] = sumgt; __syncthreads();
    for (int s = 128; s > 0; s >>= 1) { if (t < s) redf[t] += redf[t + s]; __syncthreads(); }
    float sum_gt_row = redf[0];
    __syncthreads();
    int m = s_cand_n;
    bool useLds = (m <= CAP);
    unsigned pref = ((unsigned)bin) << HSHIFT;
    unsigned resolved = 0xFFFFFFFFu << HSHIFT;
    int kk = kk0;
    const int shifts[3] = {12, 4, 0};
    const int nbins[3] = {256, 256, 16};
    for (int pass = 0; pass < 3; ++pass) {
        int sh = shifts[pass], nb = nbins[pass];
        for (int i = t; i < nb; i += 256) hist2[i] = 0;
        __syncthreads();
        if (useLds) {
            for (int i = t; i < m; i += 256) {
                unsigned u = cand[i];
                if ((u & resolved) == pref) atomicAdd(&hist2[(u >> sh) & (nb - 1)], 1);
            }
        } else {
            for (int p = t; p < P; p += 256) {
                unsigned u = __float_as_uint(r[p]);
                if ((u & resolved) == pref) atomicAdd(&hist2[(u >> sh) & (nb - 1)], 1);
            }
        }
        __syncthreads();
        if (t == 0) {
            int cum = 0, d = 0, kn = kk;
            for (int i = nb - 1; i >= 0; --i) {
                if (cum + hist2[i] >= kk) { d = i; kn = kk - cum; break; }
                cum += hist2[i];
            }
            s_bin = d; s_kk = kn;
        }
        __syncthreads();
        pref |= ((unsigned)s_bin) << sh;
        resolved |= (unsigned)(nb - 1) << sh;
        kk = s_kk;
        __syncthreads();
    }
    float tv = __uint_as_float(pref);    // exact k-th largest value
    float sumS = 0.f; int cntS = 0;
    if (useLds) {
        for (int i = t; i < m; i += 256) {
            float v = __uint_as_float(cand[i]);
            if (v > tv) { sumS += v; cntS++; }
        }
    } else {
        for (int p = t; p < P; p += 256) {
            unsigned u = __float_as_uint(r[p]);
            if ((u >> HSHIFT) == (unsigned)bin) {
                float v = __uint_as_float(u);
                if (v > tv) { sumS += v; cntS++; }
            }
        }
    }
    redf[t] = sumS; redi[t] = cntS; __syncthreads();
    for (int s = 128; s > 0; s >>= 1) {
        if (t < s) { redf[t] += redf[t + s]; redi[t] += redi[t + s]; }
        __syncthreads();
    }
    if (t == 0) topk[b] = sum_gt_row + redf[0] + (float)(kk0 - redi[0]) * tv;
}

// ---------------- Kernel F: finalize
__global__ void kF_final(const int* __restrict__ num_pos, const float* __restrict__ pos_ce,
                         const float* __restrict__ topk, const float* __restrict__ gsum,
                         const int* __restrict__ num_pos1_tot, float* __restrict__ out) {
    if (threadIdx.x != 0 || blockIdx.x != 0) return;
    int np = 0; float lc = 0.f;
    for (int b = 0; b < B; ++b) { np += num_pos[b]; lc += pos_ce[b] + topk[b]; }
    float N = fmaxf((float)np, 1.f);
    float N1 = fmaxf((float)(*num_pos1_tot), 1.f);
    out[0] = gsum[0] / N;
    out[1] = lc / N;
    out[2] = gsum[1] / N1;
}

extern "C" void kernel_launch(void* const* d_in, const int* in_sizes, int n_in,
                              void* d_out, int out_size, void* d_ws, size_t ws_size,
                              hipStream_t stream) {
    const float* loc_data   = (const float*)d_in[0];
    const float* conf_data  = (const float*)d_in[1];
    const float* landm_data = (const float*)d_in[2];
    const float* priors     = (const float*)d_in[3];
    const float* targets    = (const float*)d_in[4];
    float* out = (float*)d_out;

    char* ws = (char*)d_ws;
    size_t off = 0;
    auto alloc = [&](size_t bytes) -> void* {
        void* p = ws + off;
        off += (bytes + 255) & ~(size_t)255;
        return p;
    };
    float* bt_ov    = (float*)alloc((size_t)B * P * 4);
    int*   bt_idx   = (int*)  alloc((size_t)B * P * 4);
    float* rank     = (float*)alloc((size_t)B * P * 4);
    unsigned long long* bp_part = (unsigned long long*)alloc((size_t)B * O * SPLIT * 8);
    size_t hist_bytes = (size_t)B * HB * 4;
    int*   hist = (int*)alloc(hist_bytes);
    size_t acc_bytes = (size_t)(B * 4 * 4 + 16);
    char* acc = (char*)alloc(acc_bytes);
    int*   any_valid    = (int*)acc;
    int*   num_pos      = (int*)(acc + B * 4);
    float* pos_ce       = (float*)(acc + 2 * B * 4);
    float* topk         = (float*)(acc + 3 * B * 4);
    float* gsum         = (float*)(acc + 4 * B * 4);
    int*   num_pos1_tot = (int*)(acc + 4 * B * 4 + 8);

    hipMemsetAsync(hist, 0, hist_bytes + 256 /*align pad*/ + acc_bytes, stream);

    kA_best_truth<<<dim3(B * NCHUNK), dim3(256), 0, stream>>>(priors, targets, bt_ov, bt_idx);
    kB_best_prior<<<dim3(B * (O / TG) * SPLIT), dim3(256), 0, stream>>>(priors, targets, bp_part);
    kC_scatter<<<dim3(B), dim3(64), 0, stream>>>(bp_part, bt_ov, bt_idx, any_valid);
    kD_main<<<dim3(B * NCHUNK), dim3(256), 0, stream>>>(loc_data, conf_data, landm_data, priors,
                                                        targets, bt_ov, bt_idx, any_valid, rank,
                                                        hist, num_pos, pos_ce, gsum, num_pos1_tot);
    kE_topk<<<dim3(B), dim3(256), 0, stream>>>(rank, hist, num_pos, topk);
    kF_final<<<dim3(1), dim3(64), 0, stream>>>(num_pos, pos_ce, topk, gsum, num_pos1_tot, out);
}

// Round 5
// 287.943 us; speedup vs baseline: 1.3424x; 1.0336x over previous
//
#include <hip/hip_runtime.h>
#include <math.h>

#define B 64
#define P 16800
#define O 64
#define NCHUNK 66          // ceil(16800/256)
#define THRESH 0.35f
#define VALID_T 0.2f
#define HB 4096            // coarse hist bins = top 12 bits of float bits (rank >= 0)
#define HSHIFT 20
#define TG 8               // truths per kB block
#define SPLIT 4            // prior-range splits in kB
#define PCH (P / SPLIT)    // 4200
#define ESPLIT 16          // row splits in kE1
#define PSEG ((P + ESPLIT - 1) / ESPLIT)   // 1050
#define CCAP 4096          // per-row global candidate capacity

__device__ __forceinline__ float smooth_l1(float x) {
    float ax = fabsf(x);
    return ax < 1.f ? 0.5f * ax * ax : ax - 0.5f;
}

__device__ __forceinline__ float wave_sum(float v) {
#pragma unroll
    for (int s = 32; s > 0; s >>= 1) v += __shfl_down(v, s, 64);
    return v;
}
__device__ __forceinline__ int wave_sum_i(int v) {
#pragma unroll
    for (int s = 32; s > 0; s >>= 1) v += __shfl_down(v, s, 64);
    return v;
}

// ---------------- Kernel A: per-prior best truth (argmax over O, first-max tie-break).
__global__ void kA_best_truth(const float* __restrict__ priors,
                              const float* __restrict__ targets,
                              float* __restrict__ bt_ov, int* __restrict__ bt_idx) {
    int chunk = blockIdx.x % NCHUNK;
    int b = blockIdx.x / NCHUNK;
    __shared__ float tx1[O], ty1[O], tx2[O], ty2[O], ta[O];
    if (threadIdx.x < O) {
        const float* t = &targets[(b * O + threadIdx.x) * 15];
        float a0 = t[0], a1 = t[1], a2 = t[2], a3 = t[3];
        tx1[threadIdx.x] = a0; ty1[threadIdx.x] = a1;
        tx2[threadIdx.x] = a2; ty2[threadIdx.x] = a3;
        ta[threadIdx.x] = (a2 - a0) * (a3 - a1);
    }
    __syncthreads();
    int p = chunk * 256 + threadIdx.x;
    if (p >= P) return;
    float4 pr = ((const float4*)priors)[p];
    float px1 = pr.x - pr.z * 0.5f, py1 = pr.y - pr.w * 0.5f;
    float px2 = pr.x + pr.z * 0.5f, py2 = pr.y + pr.w * 0.5f;
    float area_b = (px2 - px1) * (py2 - py1);
    float best = 0.f; int bi = 0;    // all-zero row -> argmax = 0, ov = 0 (matches ref)
    for (int o = 0; o < O; ++o) {
        float w = fmaxf(fminf(tx2[o], px2) - fmaxf(tx1[o], px1), 0.f);
        float h = fmaxf(fminf(ty2[o], py2) - fmaxf(ty1[o], py1), 0.f);
        float inter = w * h;
        if (__any(inter > 0.f)) {
            float iou = inter / (ta[o] + area_b - inter);
            if (iou > best) { best = iou; bi = o; }   // strict >: first max wins
        }
    }
    bt_ov[b * P + p] = best;
    bt_idx[b * P + p] = bi;
}

// ---------------- Kernel B: per-truth best prior, partial over a P-split.
__global__ void __launch_bounds__(256) kB_best_prior(
        const float* __restrict__ priors, const float* __restrict__ targets,
        unsigned long long* __restrict__ bp_part) {
    int s = blockIdx.x % SPLIT;
    int g = (blockIdx.x / SPLIT) % (O / TG);
    int b = blockIdx.x / (SPLIT * (O / TG));
    float tx1[TG], ty1[TG], tx2[TG], ty2[TG], ta[TG];
#pragma unroll
    for (int o = 0; o < TG; ++o) {
        const float* t = &targets[(b * O + g * TG + o) * 15];
        tx1[o] = t[0]; ty1[o] = t[1]; tx2[o] = t[2]; ty2[o] = t[3];
        ta[o] = (tx2[o] - tx1[o]) * (ty2[o] - ty1[o]);
    }
    int p0 = s * PCH;
    float best[TG]; int bp[TG];
#pragma unroll
    for (int o = 0; o < TG; ++o) { best[o] = 0.f; bp[o] = p0 + (int)threadIdx.x; }
    for (int p = p0 + (int)threadIdx.x; p < p0 + PCH; p += 256) {
        float4 pr = ((const float4*)priors)[p];
        float px1 = pr.x - pr.z * 0.5f, py1 = pr.y - pr.w * 0.5f;
        float px2 = pr.x + pr.z * 0.5f, py2 = pr.y + pr.w * 0.5f;
        float area_b = (px2 - px1) * (py2 - py1);
#pragma unroll
        for (int o = 0; o < TG; ++o) {
            float w = fmaxf(fminf(tx2[o], px2) - fmaxf(tx1[o], px1), 0.f);
            float h = fmaxf(fminf(ty2[o], py2) - fmaxf(ty1[o], py1), 0.f);
            float inter = w * h;
            if (__any(inter > 0.f)) {
                float iou = inter / (ta[o] + area_b - inter);
                if (iou > best[o]) { best[o] = iou; bp[o] = p; }  // ascending p: first max
            }
        }
    }
    __shared__ unsigned long long wk[4][TG];
    int wid = threadIdx.x >> 6, lid = threadIdx.x & 63;
#pragma unroll
    for (int o = 0; o < TG; ++o) {
        unsigned long long key = ((unsigned long long)__float_as_uint(best[o]) << 32)
                               | (unsigned)(0xFFFFFFFFu - (unsigned)bp[o]);
#pragma unroll
        for (int sft = 32; sft > 0; sft >>= 1) {
            unsigned long long other = __shfl_down(key, sft, 64);
            if (other > key) key = other;
        }
        if (lid == 0) wk[wid][o] = key;
    }
    __syncthreads();
    if (threadIdx.x < TG) {
        unsigned long long k0 = wk[0][threadIdx.x];
#pragma unroll
        for (int w = 1; w < 4; ++w) {
            unsigned long long kw = wk[w][threadIdx.x];
            if (kw > k0) k0 = kw;
        }
        bp_part[(size_t)(b * O + g * TG + threadIdx.x) * SPLIT + s] = k0;
    }
}

// ---------------- Kernel C: finish kB reduction + scatter overrides, one wave per row.
__global__ void kC_scatter(const unsigned long long* __restrict__ bp_part,
                           float* __restrict__ bt_ov, int* __restrict__ bt_idx,
                           int* __restrict__ any_valid) {
    int b = blockIdx.x;
    int j = threadIdx.x;              // 0..63, one truth per lane
    unsigned long long k = bp_part[(size_t)(b * O + j) * SPLIT];
#pragma unroll
    for (int s = 1; s < SPLIT; ++s) {
        unsigned long long kw = bp_part[(size_t)(b * O + j) * SPLIT + s];
        if (kw > k) k = kw;
    }
    int p = (int)(0xFFFFFFFFu - (unsigned)(k & 0xFFFFFFFFu));
    float iou = __uint_as_float((unsigned)(k >> 32));
    int v = (iou >= VALID_T) ? 1 : 0;
    __shared__ int sp[O];
    sp[j] = p;
    float orig = bt_ov[b * P + p];    // pre-scatter value (depends only on p)
    __syncthreads();                  // all reads done before any write
    bool winner = true;
    for (int jj = j + 1; jj < O; ++jj)
        if (sp[jj] == p) { winner = false; break; }
    if (winner) {                     // winner == last j writing this p (numpy semantics)
        bt_ov[b * P + p] = v ? 2.0f : orig;
        bt_idx[b * P + p] = j;        // unconditional, even for invalid truths
    }
    unsigned long long av = __ballot(v != 0);
    if (j == 0) any_valid[b] = (av != 0ULL) ? 1 : 0;
}

// ---------------- Kernel D: per-prior losses + CE + rank score + coarse rank histogram.
__global__ void kD_main(const float* __restrict__ loc_data, const float* __restrict__ conf_data,
                        const float* __restrict__ landm_data, const float* __restrict__ priors,
                        const float* __restrict__ targets,
                        const float* __restrict__ bt_ov, const int* __restrict__ bt_idx,
                        const int* __restrict__ any_valid,
                        float* __restrict__ rank, int* __restrict__ hist,
                        int* __restrict__ num_pos, float* __restrict__ pos_ce,
                        float* __restrict__ gsum, int* __restrict__ num_pos1_tot) {
    int chunk = blockIdx.x % NCHUNK;
    int b = blockIdx.x / NCHUNK;
    __shared__ float tg[O * 15];
    __shared__ int lhist[HB];
    __shared__ float wredf[3][4];
    __shared__ int wredi[2][4];
    for (int i = threadIdx.x; i < O * 15; i += blockDim.x) tg[i] = targets[b * O * 15 + i];
    for (int i = threadIdx.x; i < HB; i += blockDim.x) lhist[i] = 0;
    __syncthreads();
    int p = chunk * 256 + threadIdx.x;
    float ll = 0.f, llm = 0.f, cep = 0.f;
    int cp = 0, cp1 = 0;
    if (p < P) {
        float ov = bt_ov[b * P + p];
        int ti = bt_idx[b * P + p];
        int conf = 0;
        if (any_valid[b] && ov >= THRESH) conf = (int)tg[ti * 15 + 14];   // label is +-1.0 exactly
        float2 c01 = ((const float2*)conf_data)[b * P + p];
        float c0 = c01.x, c1 = c01.y;
        float m = fmaxf(c0, c1);
        float lse = m + logf(expf(c0 - m) + expf(c1 - m));
        bool pos = conf != 0;
        float ce = lse - (pos ? c1 : c0);
        float rv = pos ? 0.f : ce;
        rank[b * P + p] = rv;
        atomicAdd(&lhist[__float_as_uint(rv) >> HSHIFT], 1);
        if (pos) {
            cp = 1; cep = ce;
            float4 pr = ((const float4*)priors)[p];
            float cx = pr.x, cy = pr.y, sw = pr.z, sh = pr.w;
            const float* t = &tg[ti * 15];
            float gx = ((t[0] + t[2]) * 0.5f - cx) / (0.1f * sw);
            float gy = ((t[1] + t[3]) * 0.5f - cy) / (0.1f * sh);
            float gw = logf((t[2] - t[0]) / sw) / 0.2f;
            float gh = logf((t[3] - t[1]) / sh) / 0.2f;
            const float* ld = &loc_data[(size_t)(b * P + p) * 4];
            ll = smooth_l1(ld[0] - gx) + smooth_l1(ld[1] - gy) +
                 smooth_l1(ld[2] - gw) + smooth_l1(ld[3] - gh);
            if (conf > 0) {
                cp1 = 1;
                const float* lmd = &landm_data[(size_t)(b * P + p) * 10];
                for (int k5 = 0; k5 < 5; ++k5) {
                    float lx = (t[4 + k5 * 2 + 0] - cx) / (0.1f * sw);
                    float ly = (t[4 + k5 * 2 + 1] - cy) / (0.1f * sh);
                    llm += smooth_l1(lmd[k5 * 2 + 0] - lx) + smooth_l1(lmd[k5 * 2 + 1] - ly);
                }
            }
        }
    }
    int wid = threadIdx.x >> 6, lid = threadIdx.x & 63;
    float s_ll = wave_sum(ll), s_llm = wave_sum(llm), s_cep = wave_sum(cep);
    int s_cp = wave_sum_i(cp), s_cp1 = wave_sum_i(cp1);
    if (lid == 0) {
        wredf[0][wid] = s_ll; wredf[1][wid] = s_llm; wredf[2][wid] = s_cep;
        wredi[0][wid] = s_cp; wredi[1][wid] = s_cp1;
    }
    __syncthreads();
    if (threadIdx.x == 0) {
        float ll_t = wredf[0][0] + wredf[0][1] + wredf[0][2] + wredf[0][3];
        float llm_t = wredf[1][0] + wredf[1][1] + wredf[1][2] + wredf[1][3];
        float cep_t = wredf[2][0] + wredf[2][1] + wredf[2][2] + wredf[2][3];
        int cp_t = wredi[0][0] + wredi[0][1] + wredi[0][2] + wredi[0][3];
        int cp1_t = wredi[1][0] + wredi[1][1] + wredi[1][2] + wredi[1][3];
        if (ll_t != 0.f)  atomicAdd(&gsum[0], ll_t);
        if (llm_t != 0.f) atomicAdd(&gsum[1], llm_t);
        if (cep_t != 0.f) atomicAdd(&pos_ce[b], cep_t);
        if (cp_t)  atomicAdd(&num_pos[b], cp_t);
        if (cp1_t) atomicAdd(num_pos1_tot, cp1_t);
    }
    int* gh = hist + (size_t)b * HB;
#pragma unroll
    for (int i = threadIdx.x; i < HB; i += 256) {
        int c = lhist[i];
        if (c) atomicAdd(&gh[i], c);
    }
}

// ---------------- Kernel E0: per-row coarse-bin selection from hist.
__global__ void kE0_findbin(const int* __restrict__ hist, const int* __restrict__ num_pos,
                            int* __restrict__ binArr, int* __restrict__ kkArr) {
    int b = blockIdx.x;
    const int* h = hist + (size_t)b * HB;
    int k = num_pos[b] * 7;
    if (k > P - 1) k = P - 1;
    __shared__ int chunkSum[256];
    int t = threadIdx.x;
    int cs = 0;
#pragma unroll
    for (int i = 0; i < HB / 256; ++i) cs += h[t * (HB / 256) + i];
    chunkSum[t] = cs;
    __syncthreads();
    if (t == 0) {
        if (k <= 0) { binArr[b] = -1; kkArr[b] = 0; return; }
        int cum = 0, bin = 0, kk = k;
        for (int c = 255; c >= 0; --c) {
            if (cum + chunkSum[c] >= k) {
                for (int i = HB / 256 - 1; i >= 0; --i) {
                    int hv = h[c * (HB / 256) + i];
                    if (cum + hv >= k) { bin = c * (HB / 256) + i; kk = k - cum; goto found; }
                    cum += hv;
                }
            }
            cum += chunkSum[c];
        }
    found:
        binArr[b] = bin; kkArr[b] = kk;
    }
}

// ---------------- Kernel E1: parallel row scan — partial sum of above-bin values +
// candidate gather (LDS compaction, one global reservation per block).
__global__ void kE1_scan(const float* __restrict__ rank, const int* __restrict__ binArr,
                         float* __restrict__ sumgt_part, unsigned* __restrict__ cand,
                         int* __restrict__ cand_cnt) {
    int seg = blockIdx.x % ESPLIT;
    int b = blockIdx.x / ESPLIT;
    int bin = binArr[b];
    if (bin < 0) return;
    const float* r = rank + (size_t)b * P;
    unsigned lo_bound = ((unsigned)(bin + 1)) << HSHIFT;
    __shared__ unsigned lc[PSEG];
    __shared__ int lcnt, gbase;
    __shared__ float wred[4];
    int t = threadIdx.x;
    if (t == 0) lcnt = 0;
    __syncthreads();
    int pend = min((seg + 1) * PSEG, P);
    float sumgt = 0.f;
    for (int p = seg * PSEG + t; p < pend; p += 256) {
        float v = r[p];
        unsigned u = __float_as_uint(v);
        if (u >= lo_bound) sumgt += v;
        else if ((u >> HSHIFT) == (unsigned)bin) {
            int idx = atomicAdd(&lcnt, 1);
            lc[idx] = u;
        }
    }
    __syncthreads();
    if (t == 0 && lcnt > 0) gbase = atomicAdd(&cand_cnt[b], lcnt);
    int wid = t >> 6, lid = t & 63;
    float s = wave_sum(sumgt);
    if (lid == 0) wred[wid] = s;
    __syncthreads();
    int n = lcnt, g0 = (n > 0) ? gbase : 0;
    for (int i = t; i < n; i += 256) {
        int d = g0 + i;
        if (d < CCAP) cand[(size_t)b * CCAP + d] = lc[i];
    }
    if (t == 0) {
        float tot = wred[0] + wred[1] + wred[2] + wred[3];
        if (tot != 0.f) atomicAdd(&sumgt_part[b], tot);
    }
}

// ---------------- Kernel E2: resolve remaining 20 bits over candidate list + final sum.
__global__ void kE2_resolve(const float* __restrict__ rank, const unsigned* __restrict__ cand,
                            const int* __restrict__ cand_cnt, const int* __restrict__ binArr,
                            const int* __restrict__ kkArr, const float* __restrict__ sumgt_part,
                            float* __restrict__ topk) {
    int b = blockIdx.x;
    int bin = binArr[b];
    if (bin < 0) return;                    // topk pre-zeroed
    int m = cand_cnt[b];
    int kk0 = kkArr[b];
    const unsigned* cd = cand + (size_t)b * CCAP;
    const float* r = rank + (size_t)b * P;
    bool useG = (m > CCAP);                 // pathological overflow: rescan row
    __shared__ unsigned lcand[CCAP];
    __shared__ int hist2[256];
    __shared__ int s_bin, s_kk;
    __shared__ float redf[256];
    __shared__ int redi[256];
    int t = threadIdx.x;
    if (!useG)
        for (int i = t; i < m; i += 256) lcand[i] = cd[i];
    __syncthreads();
    unsigned pref = ((unsigned)bin) << HSHIFT;
    unsigned resolved = 0xFFFFFFFFu << HSHIFT;
    int kk = kk0;
    const int shifts[3] = {12, 4, 0};
    const int nbins[3] = {256, 256, 16};
    for (int pass = 0; pass < 3; ++pass) {
        int sh = shifts[pass], nb = nbins[pass];
        for (int i = t; i < nb; i += 256) hist2[i] = 0;
        __syncthreads();
        if (!useG) {
            for (int i = t; i < m; i += 256) {
                unsigned u = lcand[i];
                if ((u & resolved) == pref) atomicAdd(&hist2[(u >> sh) & (nb - 1)], 1);
            }
        } else {
            for (int p = t; p < P; p += 256) {
                unsigned u = __float_as_uint(r[p]);
                if ((u & resolved) == pref) atomicAdd(&hist2[(u >> sh) & (nb - 1)], 1);
            }
        }
        __syncthreads();
        if (t == 0) {
            int cum = 0, d = 0, kn = kk;
            for (int i = nb - 1; i >= 0; --i) {
                if (cum + hist2[i] >= kk) { d = i; kn = kk - cum; break; }
                cum += hist2[i];
            }
            s_bin = d; s_kk = kn;
        }
        __syncthreads();
        pref |= ((unsigned)s_bin) << sh;
        resolved |= (unsigned)(nb - 1) << sh;
        kk = s_kk;
        __syncthreads();
    }
    float tv = __uint_as_float(pref);    // exact k-th largest value
    float sumS = 0.f; int cntS = 0;
    if (!useG) {
        for (int i = t; i < m; i += 256) {
            float v = __uint_as_float(lcand[i]);
            if (v > tv) { sumS += v; cntS++; }
        }
    } else {
        for (int p = t; p < P; p += 256) {
            unsigned u = __float_as_uint(r[p]);
            if ((u >> HSHIFT) == (unsigned)bin) {
                float v = __uint_as_float(u);
                if (v > tv) { sumS += v; cntS++; }
            }
        }
    }
    redf[t] = sumS; redi[t] = cntS; __syncthreads();
    for (int s = 128; s > 0; s >>= 1) {
        if (t < s) { redf[t] += redf[t + s]; redi[t] += redi[t + s]; }
        __syncthreads();
    }
    if (t == 0) topk[b] = sumgt_part[b] + redf[0] + (float)(kk0 - redi[0]) * tv;
}

// ---------------- Kernel F: finalize
__global__ void kF_final(const int* __restrict__ num_pos, const float* __restrict__ pos_ce,
                         const float* __restrict__ topk, const float* __restrict__ gsum,
                         const int* __restrict__ num_pos1_tot, float* __restrict__ out) {
    if (threadIdx.x != 0 || blockIdx.x != 0) return;
    int np = 0; float lc = 0.f;
    for (int b = 0; b < B; ++b) { np += num_pos[b]; lc += pos_ce[b] + topk[b]; }
    float N = fmaxf((float)np, 1.f);
    float N1 = fmaxf((float)(*num_pos1_tot), 1.f);
    out[0] = gsum[0] / N;
    out[1] = lc / N;
    out[2] = gsum[1] / N1;
}

extern "C" void kernel_launch(void* const* d_in, const int* in_sizes, int n_in,
                              void* d_out, int out_size, void* d_ws, size_t ws_size,
                              hipStream_t stream) {
    const float* loc_data   = (const float*)d_in[0];
    const float* conf_data  = (const float*)d_in[1];
    const float* landm_data = (const float*)d_in[2];
    const float* priors     = (const float*)d_in[3];
    const float* targets    = (const float*)d_in[4];
    float* out = (float*)d_out;

    char* ws = (char*)d_ws;
    size_t off = 0;
    auto alloc = [&](size_t bytes) -> void* {
        void* p = ws + off;
        off += (bytes + 255) & ~(size_t)255;
        return p;
    };
    float* bt_ov    = (float*)alloc((size_t)B * P * 4);
    int*   bt_idx   = (int*)  alloc((size_t)B * P * 4);
    float* rank     = (float*)alloc((size_t)B * P * 4);
    unsigned long long* bp_part = (unsigned long long*)alloc((size_t)B * O * SPLIT * 8);
    unsigned* cand  = (unsigned*)alloc((size_t)B * CCAP * 4);
    int* binArr     = (int*)alloc(B * 4);
    int* kkArr      = (int*)alloc(B * 4);
    // zeroed region: hist + accumulators
    size_t hist_bytes = (size_t)B * HB * 4;
    char* zbase = (char*)alloc(hist_bytes);
    int* hist = (int*)zbase;
    size_t acc_bytes = (size_t)(B * 6 * 4 + 16);
    char* acc = (char*)alloc(acc_bytes);
    int*   any_valid    = (int*)acc;
    int*   num_pos      = (int*)(acc + B * 4);
    float* pos_ce       = (float*)(acc + 2 * B * 4);
    float* topk         = (float*)(acc + 3 * B * 4);
    int*   cand_cnt     = (int*)(acc + 4 * B * 4);
    float* sumgt_part   = (float*)(acc + 5 * B * 4);
    float* gsum         = (float*)(acc + 6 * B * 4);
    int*   num_pos1_tot = (int*)(acc + 6 * B * 4 + 8);
    size_t zlen = (size_t)(acc - zbase) + acc_bytes;

    hipMemsetAsync(zbase, 0, zlen, stream);

    kA_best_truth<<<dim3(B * NCHUNK), dim3(256), 0, stream>>>(priors, targets, bt_ov, bt_idx);
    kB_best_prior<<<dim3(B * (O / TG) * SPLIT), dim3(256), 0, stream>>>(priors, targets, bp_part);
    kC_scatter<<<dim3(B), dim3(64), 0, stream>>>(bp_part, bt_ov, bt_idx, any_valid);
    kD_main<<<dim3(B * NCHUNK), dim3(256), 0, stream>>>(loc_data, conf_data, landm_data, priors,
                                                        targets, bt_ov, bt_idx, any_valid, rank,
                                                        hist, num_pos, pos_ce, gsum, num_pos1_tot);
    kE0_findbin<<<dim3(B), dim3(256), 0, stream>>>(hist, num_pos, binArr, kkArr);
    kE1_scan<<<dim3(B * ESPLIT), dim3(256), 0, stream>>>(rank, binArr, sumgt_part, cand, cand_cnt);
    kE2_resolve<<<dim3(B), dim3(256), 0, stream>>>(rank, cand, cand_cnt, binArr, kkArr,
                                                   sumgt_part, topk);
    kF_final<<<dim3(1), dim3(64), 0, stream>>>(num_pos, pos_ce, topk, gsum, num_pos1_tot, out);
}

// Round 6
// 283.384 us; speedup vs baseline: 1.3640x; 1.0161x over previous
//
#include <hip/hip_runtime.h>
#include <math.h>

#define B 64
#define P 16800
#define O 64
#define THRESH 0.35f
#define VALID_T 0.2f
#define HB 4096            // coarse hist bins = top 12 bits of float bits (rank >= 0)
#define HSHIFT 20
#define TG 8               // truths per kB block
#define SPLIT 4            // prior-range splits in kB
#define PCH (P / SPLIT)    // 4200
#define ESPLIT 16          // row splits in kE1
#define PSEG ((P + ESPLIT - 1) / ESPLIT)   // 1050
#define CCAP 4096          // per-row global candidate capacity
#define MULT 6             // chunks of 256 per kD block
#define CHB (MULT * 256)   // 1536 priors per kD block
#define NB2 ((P + CHB - 1) / CHB)          // 11 blocks per row
#define BMW ((P + 31) / 32)                // 525 bitmap words per row

__device__ __forceinline__ float smooth_l1(float x) {
    float ax = fabsf(x);
    return ax < 1.f ? 0.5f * ax * ax : ax - 0.5f;
}

__device__ __forceinline__ float wave_sum(float v) {
#pragma unroll
    for (int s = 32; s > 0; s >>= 1) v += __shfl_down(v, s, 64);
    return v;
}
__device__ __forceinline__ int wave_sum_i(int v) {
#pragma unroll
    for (int s = 32; s > 0; s >>= 1) v += __shfl_down(v, s, 64);
    return v;
}

// ---------------- Kernel B: per-truth best prior, partial over a P-split.
__global__ void __launch_bounds__(256) kB_best_prior(
        const float* __restrict__ priors, const float* __restrict__ targets,
        unsigned long long* __restrict__ bp_part) {
    int s = blockIdx.x % SPLIT;
    int g = (blockIdx.x / SPLIT) % (O / TG);
    int b = blockIdx.x / (SPLIT * (O / TG));
    float tx1[TG], ty1[TG], tx2[TG], ty2[TG], ta[TG];
#pragma unroll
    for (int o = 0; o < TG; ++o) {
        const float* t = &targets[(b * O + g * TG + o) * 15];
        tx1[o] = t[0]; ty1[o] = t[1]; tx2[o] = t[2]; ty2[o] = t[3];
        ta[o] = (tx2[o] - tx1[o]) * (ty2[o] - ty1[o]);
    }
    int p0 = s * PCH;
    float best[TG]; int bp[TG];
#pragma unroll
    for (int o = 0; o < TG; ++o) { best[o] = 0.f; bp[o] = p0 + (int)threadIdx.x; }
    for (int p = p0 + (int)threadIdx.x; p < p0 + PCH; p += 256) {
        float4 pr = ((const float4*)priors)[p];
        float px1 = pr.x - pr.z * 0.5f, py1 = pr.y - pr.w * 0.5f;
        float px2 = pr.x + pr.z * 0.5f, py2 = pr.y + pr.w * 0.5f;
        float area_b = (px2 - px1) * (py2 - py1);
#pragma unroll
        for (int o = 0; o < TG; ++o) {
            float w = fmaxf(fminf(tx2[o], px2) - fmaxf(tx1[o], px1), 0.f);
            float h = fmaxf(fminf(ty2[o], py2) - fmaxf(ty1[o], py1), 0.f);
            float inter = w * h;
            if (__any(inter > 0.f)) {
                float iou = inter / (ta[o] + area_b - inter);
                if (iou > best[o]) { best[o] = iou; bp[o] = p; }  // ascending p: first max
            }
        }
    }
    __shared__ unsigned long long wk[4][TG];
    int wid = threadIdx.x >> 6, lid = threadIdx.x & 63;
#pragma unroll
    for (int o = 0; o < TG; ++o) {
        unsigned long long key = ((unsigned long long)__float_as_uint(best[o]) << 32)
                               | (unsigned)(0xFFFFFFFFu - (unsigned)bp[o]);
#pragma unroll
        for (int sft = 32; sft > 0; sft >>= 1) {
            unsigned long long other = __shfl_down(key, sft, 64);
            if (other > key) key = other;
        }
        if (lid == 0) wk[wid][o] = key;
    }
    __syncthreads();
    if (threadIdx.x < TG) {
        unsigned long long k0 = wk[0][threadIdx.x];
#pragma unroll
        for (int w = 1; w < 4; ++w) {
            unsigned long long kw = wk[w][threadIdx.x];
            if (kw > k0) k0 = kw;
        }
        bp_part[(size_t)(b * O + g * TG + threadIdx.x) * SPLIT + s] = k0;
    }
}

// ---------------- Kernel C: finish kB reduction; emit per-row override bitmap +
// winner list (last-write-wins already resolved here). One wave per row.
__global__ void kC_scatter(const unsigned long long* __restrict__ bp_part,
                           unsigned* __restrict__ bitmap,
                           int* __restrict__ ov_p, int* __restrict__ ov_v,
                           int* __restrict__ any_valid) {
    int b = blockIdx.x;
    int j = threadIdx.x;              // 0..63, one truth per lane
    unsigned* bm = bitmap + (size_t)b * BMW;
    for (int i = j; i < BMW; i += 64) bm[i] = 0u;
    unsigned long long k = bp_part[(size_t)(b * O + j) * SPLIT];
#pragma unroll
    for (int s = 1; s < SPLIT; ++s) {
        unsigned long long kw = bp_part[(size_t)(b * O + j) * SPLIT + s];
        if (kw > k) k = kw;
    }
    int p = (int)(0xFFFFFFFFu - (unsigned)(k & 0xFFFFFFFFu));
    float iou = __uint_as_float((unsigned)(k >> 32));
    int v = (iou >= VALID_T) ? 1 : 0;
    __shared__ int sp[O];
    sp[j] = p;
    __syncthreads();                  // also orders bm zeroing before atomics
    bool winner = true;               // winner == last j with this p (numpy semantics)
    for (int jj = j + 1; jj < O; ++jj)
        if (sp[jj] == p) { winner = false; break; }
    ov_p[b * O + j] = winner ? p : -1;
    ov_v[b * O + j] = v;
    if (winner) atomicOr(&bm[p >> 5], 1u << (p & 31));
    unsigned long long av = __ballot(v != 0);
    if (j == 0) any_valid[b] = (av != 0ULL) ? 1 : 0;
}

// ---------------- Kernel D (fused kA+kD): per-prior best-truth argmax computed
// inline, overrides applied from bitmap+list; losses, CE, rank, coarse hist.
// Each block covers CHB=1536 priors to amortize LDS hist + reductions.
__global__ void kD_main(const float* __restrict__ loc_data, const float* __restrict__ conf_data,
                        const float* __restrict__ landm_data, const float* __restrict__ priors,
                        const float* __restrict__ targets,
                        const unsigned* __restrict__ bitmap,
                        const int* __restrict__ ov_p, const int* __restrict__ ov_v,
                        const int* __restrict__ any_valid,
                        float* __restrict__ rank, int* __restrict__ hist,
                        int* __restrict__ num_pos, float* __restrict__ pos_ce,
                        float* __restrict__ gsum, int* __restrict__ num_pos1_tot) {
    int blk = blockIdx.x % NB2;
    int b = blockIdx.x / NB2;
    int p0 = blk * CHB;
    __shared__ float tx1[O], ty1[O], tx2[O], ty2[O], ta[O], lab[O];
    __shared__ float lm[O][10];
    __shared__ unsigned bms[CHB / 32];
    __shared__ int sovp[O], sovv[O];
    __shared__ int lhist[HB];
    __shared__ float wredf[3][4];
    __shared__ int wredi[2][4];
    int tid = threadIdx.x;
    if (tid < O) {
        const float* t = &targets[(b * O + tid) * 15];
        float a0 = t[0], a1 = t[1], a2 = t[2], a3 = t[3];
        tx1[tid] = a0; ty1[tid] = a1; tx2[tid] = a2; ty2[tid] = a3;
        ta[tid] = (a2 - a0) * (a3 - a1);
        lab[tid] = t[14];
        sovp[tid] = ov_p[b * O + tid];
        sovv[tid] = ov_v[b * O + tid];
    } else if (tid < O + CHB / 32) {
        int w = (p0 >> 5) + (tid - O);
        bms[tid - O] = (w < BMW) ? bitmap[(size_t)b * BMW + w] : 0u;
    }
    for (int i = tid; i < O * 10; i += 256) lm[i / 10][i % 10] = targets[b * O * 15 + (i / 10) * 15 + 4 + (i % 10)];
    for (int i = tid; i < HB; i += 256) lhist[i] = 0;
    __syncthreads();
    int av = any_valid[b];
    float ll = 0.f, llm = 0.f, cep = 0.f;
    int cp = 0, cp1 = 0;
#pragma unroll
    for (int mi = 0; mi < MULT; ++mi) {
        int p = p0 + mi * 256 + tid;
        if (p >= P) break;
        float4 pr = ((const float4*)priors)[p];
        float px1 = pr.x - pr.z * 0.5f, py1 = pr.y - pr.w * 0.5f;
        float px2 = pr.x + pr.z * 0.5f, py2 = pr.y + pr.w * 0.5f;
        float area_b = (px2 - px1) * (py2 - py1);
        float best = 0.f; int bi = 0;    // all-zero row -> argmax 0, ov 0 (matches ref)
        for (int o = 0; o < O; ++o) {
            float w = fmaxf(fminf(tx2[o], px2) - fmaxf(tx1[o], px1), 0.f);
            float h = fmaxf(fminf(ty2[o], py2) - fmaxf(ty1[o], py1), 0.f);
            float inter = w * h;
            if (__any(inter > 0.f)) {
                float iou = inter / (ta[o] + area_b - inter);
                if (iou > best) { best = iou; bi = o; }   // strict >: first max wins
            }
        }
        int ti = bi; float ov = best;
        if (bms[(p - p0) >> 5] & (1u << (p & 31))) {     // scatter override (<=64/row)
            for (int j = 0; j < O; ++j)
                if (sovp[j] == p) { ti = j; ov = sovv[j] ? 2.0f : best; break; }
        }
        int conf = 0;
        if (av && ov >= THRESH) conf = (int)lab[ti];      // label is +-1.0 exactly
        float2 c01 = ((const float2*)conf_data)[b * P + p];
        float c0 = c01.x, c1 = c01.y;
        float m = fmaxf(c0, c1);
        float lse = m + logf(expf(c0 - m) + expf(c1 - m));
        bool pos = conf != 0;
        float ce = lse - (pos ? c1 : c0);
        float rv = pos ? 0.f : ce;
        rank[b * P + p] = rv;
        atomicAdd(&lhist[__float_as_uint(rv) >> HSHIFT], 1);
        if (pos) {
            cp++; cep += ce;
            float cx = pr.x, cy = pr.y, sw = pr.z, sh = pr.w;
            float gx = ((tx1[ti] + tx2[ti]) * 0.5f - cx) / (0.1f * sw);
            float gy = ((ty1[ti] + ty2[ti]) * 0.5f - cy) / (0.1f * sh);
            float gw = logf((tx2[ti] - tx1[ti]) / sw) / 0.2f;
            float gh = logf((ty2[ti] - ty1[ti]) / sh) / 0.2f;
            const float* ld = &loc_data[(size_t)(b * P + p) * 4];
            ll += smooth_l1(ld[0] - gx) + smooth_l1(ld[1] - gy) +
                  smooth_l1(ld[2] - gw) + smooth_l1(ld[3] - gh);
            if (conf > 0) {
                cp1++;
                const float* lmd = &landm_data[(size_t)(b * P + p) * 10];
                for (int k5 = 0; k5 < 5; ++k5) {
                    float lx = (lm[ti][k5 * 2 + 0] - cx) / (0.1f * sw);
                    float ly = (lm[ti][k5 * 2 + 1] - cy) / (0.1f * sh);
                    llm += smooth_l1(lmd[k5 * 2 + 0] - lx) + smooth_l1(lmd[k5 * 2 + 1] - ly);
                }
            }
        }
    }
    int wid = tid >> 6, lid = tid & 63;
    float s_ll = wave_sum(ll), s_llm = wave_sum(llm), s_cep = wave_sum(cep);
    int s_cp = wave_sum_i(cp), s_cp1 = wave_sum_i(cp1);
    if (lid == 0) {
        wredf[0][wid] = s_ll; wredf[1][wid] = s_llm; wredf[2][wid] = s_cep;
        wredi[0][wid] = s_cp; wredi[1][wid] = s_cp1;
    }
    __syncthreads();
    if (tid == 0) {
        float ll_t = wredf[0][0] + wredf[0][1] + wredf[0][2] + wredf[0][3];
        float llm_t = wredf[1][0] + wredf[1][1] + wredf[1][2] + wredf[1][3];
        float cep_t = wredf[2][0] + wredf[2][1] + wredf[2][2] + wredf[2][3];
        int cp_t = wredi[0][0] + wredi[0][1] + wredi[0][2] + wredi[0][3];
        int cp1_t = wredi[1][0] + wredi[1][1] + wredi[1][2] + wredi[1][3];
        if (ll_t != 0.f)  atomicAdd(&gsum[0], ll_t);
        if (llm_t != 0.f) atomicAdd(&gsum[1], llm_t);
        if (cep_t != 0.f) atomicAdd(&pos_ce[b], cep_t);
        if (cp_t)  atomicAdd(&num_pos[b], cp_t);
        if (cp1_t) atomicAdd(num_pos1_tot, cp1_t);
    }
    int* gh = hist + (size_t)b * HB;
#pragma unroll
    for (int i = tid; i < HB; i += 256) {
        int c = lhist[i];
        if (c) atomicAdd(&gh[i], c);
    }
}

// ---------------- Kernel E0: per-row coarse-bin selection from hist.
__global__ void kE0_findbin(const int* __restrict__ hist, const int* __restrict__ num_pos,
                            int* __restrict__ binArr, int* __restrict__ kkArr) {
    int b = blockIdx.x;
    const int* h = hist + (size_t)b * HB;
    int k = num_pos[b] * 7;
    if (k > P - 1) k = P - 1;
    __shared__ int chunkSum[256];
    int t = threadIdx.x;
    int cs = 0;
#pragma unroll
    for (int i = 0; i < HB / 256; ++i) cs += h[t * (HB / 256) + i];
    chunkSum[t] = cs;
    __syncthreads();
    if (t == 0) {
        if (k <= 0) { binArr[b] = -1; kkArr[b] = 0; return; }
        int cum = 0, bin = 0, kk = k;
        for (int c = 255; c >= 0; --c) {
            if (cum + chunkSum[c] >= k) {
                for (int i = HB / 256 - 1; i >= 0; --i) {
                    int hv = h[c * (HB / 256) + i];
                    if (cum + hv >= k) { bin = c * (HB / 256) + i; kk = k - cum; goto found; }
                    cum += hv;
                }
            }
            cum += chunkSum[c];
        }
    found:
        binArr[b] = bin; kkArr[b] = kk;
    }
}

// ---------------- Kernel E1: parallel row scan — partial sum of above-bin values +
// candidate gather (LDS compaction, one global reservation per block).
__global__ void kE1_scan(const float* __restrict__ rank, const int* __restrict__ binArr,
                         float* __restrict__ sumgt_part, unsigned* __restrict__ cand,
                         int* __restrict__ cand_cnt) {
    int seg = blockIdx.x % ESPLIT;
    int b = blockIdx.x / ESPLIT;
    int bin = binArr[b];
    if (bin < 0) return;
    const float* r = rank + (size_t)b * P;
    unsigned lo_bound = ((unsigned)(bin + 1)) << HSHIFT;
    __shared__ unsigned lc[PSEG];
    __shared__ int lcnt, gbase;
    __shared__ float wred[4];
    int t = threadIdx.x;
    if (t == 0) lcnt = 0;
    __syncthreads();
    int pend = min((seg + 1) * PSEG, P);
    float sumgt = 0.f;
    for (int p = seg * PSEG + t; p < pend; p += 256) {
        float v = r[p];
        unsigned u = __float_as_uint(v);
        if (u >= lo_bound) sumgt += v;
        else if ((u >> HSHIFT) == (unsigned)bin) {
            int idx = atomicAdd(&lcnt, 1);
            lc[idx] = u;
        }
    }
    __syncthreads();
    if (t == 0 && lcnt > 0) gbase = atomicAdd(&cand_cnt[b], lcnt);
    int wid = t >> 6, lid = t & 63;
    float s = wave_sum(sumgt);
    if (lid == 0) wred[wid] = s;
    __syncthreads();
    int n = lcnt, g0 = (n > 0) ? gbase : 0;
    for (int i = t; i < n; i += 256) {
        int d = g0 + i;
        if (d < CCAP) cand[(size_t)b * CCAP + d] = lc[i];
    }
    if (t == 0) {
        float tot = wred[0] + wred[1] + wred[2] + wred[3];
        if (tot != 0.f) atomicAdd(&sumgt_part[b], tot);
    }
}

// ---------------- Kernel E2: resolve remaining 20 bits over candidate list + final sum.
__global__ void kE2_resolve(const float* __restrict__ rank, const unsigned* __restrict__ cand,
                            const int* __restrict__ cand_cnt, const int* __restrict__ binArr,
                            const int* __restrict__ kkArr, const float* __restrict__ sumgt_part,
                            float* __restrict__ topk) {
    int b = blockIdx.x;
    int bin = binArr[b];
    if (bin < 0) return;                    // topk pre-zeroed
    int m = cand_cnt[b];
    int kk0 = kkArr[b];
    const unsigned* cd = cand + (size_t)b * CCAP;
    const float* r = rank + (size_t)b * P;
    bool useG = (m > CCAP);                 // pathological overflow: rescan row
    __shared__ unsigned lcand[CCAP];
    __shared__ int hist2[256];
    __shared__ int s_bin, s_kk;
    __shared__ float redf[256];
    __shared__ int redi[256];
    int t = threadIdx.x;
    if (!useG)
        for (int i = t; i < m; i += 256) lcand[i] = cd[i];
    __syncthreads();
    unsigned pref = ((unsigned)bin) << HSHIFT;
    unsigned resolved = 0xFFFFFFFFu << HSHIFT;
    int kk = kk0;
    const int shifts[3] = {12, 4, 0};
    const int nbins[3] = {256, 256, 16};
    for (int pass = 0; pass < 3; ++pass) {
        int sh = shifts[pass], nb = nbins[pass];
        for (int i = t; i < nb; i += 256) hist2[i] = 0;
        __syncthreads();
        if (!useG) {
            for (int i = t; i < m; i += 256) {
                unsigned u = lcand[i];
                if ((u & resolved) == pref) atomicAdd(&hist2[(u >> sh) & (nb - 1)], 1);
            }
        } else {
            for (int p = t; p < P; p += 256) {
                unsigned u = __float_as_uint(r[p]);
                if ((u & resolved) == pref) atomicAdd(&hist2[(u >> sh) & (nb - 1)], 1);
            }
        }
        __syncthreads();
        if (t == 0) {
            int cum = 0, d = 0, kn = kk;
            for (int i = nb - 1; i >= 0; --i) {
                if (cum + hist2[i] >= kk) { d = i; kn = kk - cum; break; }
                cum += hist2[i];
            }
            s_bin = d; s_kk = kn;
        }
        __syncthreads();
        pref |= ((unsigned)s_bin) << sh;
        resolved |= (unsigned)(nb - 1) << sh;
        kk = s_kk;
        __syncthreads();
    }
    float tv = __uint_as_float(pref);    // exact k-th largest value
    float sumS = 0.f; int cntS = 0;
    if (!useG) {
        for (int i = t; i < m; i += 256) {
            float v = __uint_as_float(lcand[i]);
            if (v > tv) { sumS += v; cntS++; }
        }
    } else {
        for (int p = t; p < P; p += 256) {
            unsigned u = __float_as_uint(r[p]);
            if ((u >> HSHIFT) == (unsigned)bin) {
                float v = __uint_as_float(u);
                if (v > tv) { sumS += v; cntS++; }
            }
        }
    }
    redf[t] = sumS; redi[t] = cntS; __syncthreads();
    for (int s = 128; s > 0; s >>= 1) {
        if (t < s) { redf[t] += redf[t + s]; redi[t] += redi[t + s]; }
        __syncthreads();
    }
    if (t == 0) topk[b] = sumgt_part[b] + redf[0] + (float)(kk0 - redi[0]) * tv;
}

// ---------------- Kernel F: finalize
__global__ void kF_final(const int* __restrict__ num_pos, const float* __restrict__ pos_ce,
                         const float* __restrict__ topk, const float* __restrict__ gsum,
                         const int* __restrict__ num_pos1_tot, float* __restrict__ out) {
    if (threadIdx.x != 0 || blockIdx.x != 0) return;
    int np = 0; float lc = 0.f;
    for (int b = 0; b < B; ++b) { np += num_pos[b]; lc += pos_ce[b] + topk[b]; }
    float N = fmaxf((float)np, 1.f);
    float N1 = fmaxf((float)(*num_pos1_tot), 1.f);
    out[0] = gsum[0] / N;
    out[1] = lc / N;
    out[2] = gsum[1] / N1;
}

extern "C" void kernel_launch(void* const* d_in, const int* in_sizes, int n_in,
                              void* d_out, int out_size, void* d_ws, size_t ws_size,
                              hipStream_t stream) {
    const float* loc_data   = (const float*)d_in[0];
    const float* conf_data  = (const float*)d_in[1];
    const float* landm_data = (const float*)d_in[2];
    const float* priors     = (const float*)d_in[3];
    const float* targets    = (const float*)d_in[4];
    float* out = (float*)d_out;

    char* ws = (char*)d_ws;
    size_t off = 0;
    auto alloc = [&](size_t bytes) -> void* {
        void* p = ws + off;
        off += (bytes + 255) & ~(size_t)255;
        return p;
    };
    float* rank     = (float*)alloc((size_t)B * P * 4);
    unsigned long long* bp_part = (unsigned long long*)alloc((size_t)B * O * SPLIT * 8);
    unsigned* cand  = (unsigned*)alloc((size_t)B * CCAP * 4);
    unsigned* bitmap = (unsigned*)alloc((size_t)B * BMW * 4);   // zeroed inside kC
    int* ov_p       = (int*)alloc(B * O * 4);
    int* ov_v       = (int*)alloc(B * O * 4);
    int* binArr     = (int*)alloc(B * 4);
    int* kkArr      = (int*)alloc(B * 4);
    // zeroed region: hist + accumulators
    size_t hist_bytes = (size_t)B * HB * 4;
    char* zbase = (char*)alloc(hist_bytes);
    int* hist = (int*)zbase;
    size_t acc_bytes = (size_t)(B * 6 * 4 + 16);
    char* acc = (char*)alloc(acc_bytes);
    int*   any_valid    = (int*)acc;
    int*   num_pos      = (int*)(acc + B * 4);
    float* pos_ce       = (float*)(acc + 2 * B * 4);
    float* topk         = (float*)(acc + 3 * B * 4);
    int*   cand_cnt     = (int*)(acc + 4 * B * 4);
    float* sumgt_part   = (float*)(acc + 5 * B * 4);
    float* gsum         = (float*)(acc + 6 * B * 4);
    int*   num_pos1_tot = (int*)(acc + 6 * B * 4 + 8);
    size_t zlen = (size_t)(acc - zbase) + acc_bytes;

    hipMemsetAsync(zbase, 0, zlen, stream);

    kB_best_prior<<<dim3(B * (O / TG) * SPLIT), dim3(256), 0, stream>>>(priors, targets, bp_part);
    kC_scatter<<<dim3(B), dim3(64), 0, stream>>>(bp_part, bitmap, ov_p, ov_v, any_valid);
    kD_main<<<dim3(B * NB2), dim3(256), 0, stream>>>(loc_data, conf_data, landm_data, priors,
                                                     targets, bitmap, ov_p, ov_v, any_valid,
                                                     rank, hist, num_pos, pos_ce, gsum,
                                                     num_pos1_tot);
    kE0_findbin<<<dim3(B), dim3(256), 0, stream>>>(hist, num_pos, binArr, kkArr);
    kE1_scan<<<dim3(B * ESPLIT), dim3(256), 0, stream>>>(rank, binArr, sumgt_part, cand, cand_cnt);
    kE2_resolve<<<dim3(B), dim3(256), 0, stream>>>(rank, cand, cand_cnt, binArr, kkArr,
                                                   sumgt_part, topk);
    kF_final<<<dim3(1), dim3(64), 0, stream>>>(num_pos, pos_ce, topk, gsum, num_pos1_tot, out);
}

// Round 7
// 265.657 us; speedup vs baseline: 1.4550x; 1.0667x over previous
//
#include <hip/hip_runtime.h>
#include <math.h>

#define B 64
#define P 16800
#define O 64
#define THRESH 0.35f
#define VALID_T 0.2f
#define HB 4096            // coarse hist bins = top 12 bits of float bits (rank >= 0)
#define HSHIFT 20
#define TG 8               // truths per kB block
#define SPLIT 4            // prior-range splits in kB
#define PCH (P / SPLIT)    // 4200
#define ESPLIT 16          // row splits in kE1
#define PSEG ((P + ESPLIT - 1) / ESPLIT)   // 1050
#define CCAP 4096          // per-row global candidate capacity
#define MULT 4             // priors per thread in kD (held in registers)
#define CHB (MULT * 256)   // 1024 priors per kD block
#define NB2 ((P + CHB - 1) / CHB)          // 17 blocks per row
#define BMW ((P + 31) / 32)                // 525 bitmap words per row

__device__ __forceinline__ float smooth_l1(float x) {
    float ax = fabsf(x);
    return ax < 1.f ? 0.5f * ax * ax : ax - 0.5f;
}

__device__ __forceinline__ float wave_sum(float v) {
#pragma unroll
    for (int s = 32; s > 0; s >>= 1) v += __shfl_down(v, s, 64);
    return v;
}
__device__ __forceinline__ int wave_sum_i(int v) {
#pragma unroll
    for (int s = 32; s > 0; s >>= 1) v += __shfl_down(v, s, 64);
    return v;
}
__device__ __forceinline__ float wave_min(float v) {
#pragma unroll
    for (int s = 32; s > 0; s >>= 1) v = fminf(v, __shfl_xor(v, s, 64));
    return v;
}
__device__ __forceinline__ float wave_max(float v) {
#pragma unroll
    for (int s = 32; s > 0; s >>= 1) v = fmaxf(v, __shfl_xor(v, s, 64));
    return v;
}

// ---------------- Kernel B: per-truth best prior, partial over a P-split.
__global__ void __launch_bounds__(256) kB_best_prior(
        const float* __restrict__ priors, const float* __restrict__ targets,
        unsigned long long* __restrict__ bp_part) {
    int s = blockIdx.x % SPLIT;
    int g = (blockIdx.x / SPLIT) % (O / TG);
    int b = blockIdx.x / (SPLIT * (O / TG));
    float tx1[TG], ty1[TG], tx2[TG], ty2[TG], ta[TG];
#pragma unroll
    for (int o = 0; o < TG; ++o) {
        const float* t = &targets[(b * O + g * TG + o) * 15];
        tx1[o] = t[0]; ty1[o] = t[1]; tx2[o] = t[2]; ty2[o] = t[3];
        ta[o] = (tx2[o] - tx1[o]) * (ty2[o] - ty1[o]);
    }
    int p0 = s * PCH;
    float best[TG]; int bp[TG];
#pragma unroll
    for (int o = 0; o < TG; ++o) { best[o] = 0.f; bp[o] = p0 + (int)threadIdx.x; }
    for (int p = p0 + (int)threadIdx.x; p < p0 + PCH; p += 256) {
        float4 pr = ((const float4*)priors)[p];
        float px1 = pr.x - pr.z * 0.5f, py1 = pr.y - pr.w * 0.5f;
        float px2 = pr.x + pr.z * 0.5f, py2 = pr.y + pr.w * 0.5f;
        float area_b = (px2 - px1) * (py2 - py1);
#pragma unroll
        for (int o = 0; o < TG; ++o) {
            float w = fmaxf(fminf(tx2[o], px2) - fmaxf(tx1[o], px1), 0.f);
            float h = fmaxf(fminf(ty2[o], py2) - fmaxf(ty1[o], py1), 0.f);
            float inter = w * h;
            if (__any(inter > 0.f)) {
                float iou = inter / (ta[o] + area_b - inter);
                if (iou > best[o]) { best[o] = iou; bp[o] = p; }  // ascending p: first max
            }
        }
    }
    __shared__ unsigned long long wk[4][TG];
    int wid = threadIdx.x >> 6, lid = threadIdx.x & 63;
#pragma unroll
    for (int o = 0; o < TG; ++o) {
        unsigned long long key = ((unsigned long long)__float_as_uint(best[o]) << 32)
                               | (unsigned)(0xFFFFFFFFu - (unsigned)bp[o]);
#pragma unroll
        for (int sft = 32; sft > 0; sft >>= 1) {
            unsigned long long other = __shfl_down(key, sft, 64);
            if (other > key) key = other;
        }
        if (lid == 0) wk[wid][o] = key;
    }
    __syncthreads();
    if (threadIdx.x < TG) {
        unsigned long long k0 = wk[0][threadIdx.x];
#pragma unroll
        for (int w = 1; w < 4; ++w) {
            unsigned long long kw = wk[w][threadIdx.x];
            if (kw > k0) k0 = kw;
        }
        bp_part[(size_t)(b * O + g * TG + threadIdx.x) * SPLIT + s] = k0;
    }
}

// ---------------- Kernel C: finish kB reduction; emit per-row override bitmap +
// winner list (last-write-wins already resolved here). One wave per row.
__global__ void kC_scatter(const unsigned long long* __restrict__ bp_part,
                           unsigned* __restrict__ bitmap,
                           int* __restrict__ ov_p, int* __restrict__ ov_v,
                           int* __restrict__ any_valid) {
    int b = blockIdx.x;
    int j = threadIdx.x;              // 0..63, one truth per lane
    unsigned* bm = bitmap + (size_t)b * BMW;
    for (int i = j; i < BMW; i += 64) bm[i] = 0u;
    unsigned long long k = bp_part[(size_t)(b * O + j) * SPLIT];
#pragma unroll
    for (int s = 1; s < SPLIT; ++s) {
        unsigned long long kw = bp_part[(size_t)(b * O + j) * SPLIT + s];
        if (kw > k) k = kw;
    }
    int p = (int)(0xFFFFFFFFu - (unsigned)(k & 0xFFFFFFFFu));
    float iou = __uint_as_float((unsigned)(k >> 32));
    int v = (iou >= VALID_T) ? 1 : 0;
    __shared__ int sp[O];
    sp[j] = p;
    __syncthreads();                  // also orders bm zeroing before atomics
    bool winner = true;               // winner == last j with this p (numpy semantics)
    for (int jj = j + 1; jj < O; ++jj)
        if (sp[jj] == p) { winner = false; break; }
    ov_p[b * O + j] = winner ? p : -1;
    ov_v[b * O + j] = v;
    if (winner) atomicOr(&bm[p >> 5], 1u << (p & 31));
    unsigned long long av = __ballot(v != 0);
    if (j == 0) any_valid[b] = (av != 0ULL) ? 1 : 0;
}

// ---------------- Kernel D (fused kA+kD): o-outer / p-in-registers structure.
// Per o: ONE ds_read_b128 (truth box) + ONE ds_read_b32 (area), wave-bbox early-out.
__global__ void __launch_bounds__(256) kD_main(
        const float* __restrict__ loc_data, const float* __restrict__ conf_data,
        const float* __restrict__ landm_data, const float* __restrict__ priors,
        const float* __restrict__ targets,
        const unsigned* __restrict__ bitmap,
        const int* __restrict__ ov_p, const int* __restrict__ ov_v,
        const int* __restrict__ any_valid,
        float* __restrict__ rank, int* __restrict__ hist,
        int* __restrict__ num_pos, float* __restrict__ pos_ce,
        float* __restrict__ gsum, int* __restrict__ num_pos1_tot) {
    int blk = blockIdx.x % NB2;
    int b = blockIdx.x / NB2;
    int p0 = blk * CHB;
    __shared__ float4 t4[O];
    __shared__ float ta[O], lab[O];
    __shared__ float lm[O][10];
    __shared__ unsigned bms[CHB / 32];
    __shared__ int sovp[O], sovv[O];
    __shared__ int lhist[HB];
    __shared__ float wredf[3][4];
    __shared__ int wredi[2][4];
    int tid = threadIdx.x;
    if (tid < O) {
        const float* t = &targets[(b * O + tid) * 15];
        float a0 = t[0], a1 = t[1], a2 = t[2], a3 = t[3];
        t4[tid] = make_float4(a0, a1, a2, a3);
        ta[tid] = (a2 - a0) * (a3 - a1);
        lab[tid] = t[14];
        sovp[tid] = ov_p[b * O + tid];
        sovv[tid] = ov_v[b * O + tid];
    } else if (tid < O + CHB / 32) {
        int w = (p0 >> 5) + (tid - O);
        bms[tid - O] = (w < BMW) ? bitmap[(size_t)b * BMW + w] : 0u;
    }
    for (int i = tid; i < O * 10; i += 256)
        lm[i / 10][i % 10] = targets[b * O * 15 + (i / 10) * 15 + 4 + (i % 10)];
    for (int i = tid; i < HB; i += 256) lhist[i] = 0;
    __syncthreads();
    int av = any_valid[b];
    // ---- load MULT priors into registers, compute per-wave bbox
    float px1[MULT], py1[MULT], px2[MULT], py2[MULT], areab[MULT];
    float4 pr4[MULT];
    float best[MULT]; int bi[MULT]; bool act[MULT];
    float bx1 = 1e30f, by1 = 1e30f, bx2 = -1e30f, by2 = -1e30f;
#pragma unroll
    for (int mi = 0; mi < MULT; ++mi) {
        int p = p0 + mi * 256 + tid;
        act[mi] = (p < P);
        int pc = act[mi] ? p : (P - 1);
        float4 q = ((const float4*)priors)[pc];
        pr4[mi] = q;
        px1[mi] = q.x - q.z * 0.5f; py1[mi] = q.y - q.w * 0.5f;
        px2[mi] = q.x + q.z * 0.5f; py2[mi] = q.y + q.w * 0.5f;
        areab[mi] = (px2[mi] - px1[mi]) * (py2[mi] - py1[mi]);
        bx1 = fminf(bx1, px1[mi]); by1 = fminf(by1, py1[mi]);
        bx2 = fmaxf(bx2, px2[mi]); by2 = fmaxf(by2, py2[mi]);
        best[mi] = 0.f; bi[mi] = 0;   // all-zero row -> argmax 0, ov 0 (matches ref)
    }
    bx1 = wave_min(bx1); by1 = wave_min(by1);
    bx2 = wave_max(bx2); by2 = wave_max(by2);
    // ---- argmax over truths: o outer, 2 LDS reads per o, wave-bbox early-out
    for (int o = 0; o < O; ++o) {
        float4 t = t4[o];
        float w0 = fminf(t.z, bx2) - fmaxf(t.x, bx1);
        float h0 = fminf(t.w, by2) - fmaxf(t.y, by1);
        if (w0 <= 0.f || h0 <= 0.f) continue;   // wave-uniform skip: iou==0 can't win
        float area_a = ta[o];
#pragma unroll
        for (int mi = 0; mi < MULT; ++mi) {
            float w = fmaxf(fminf(t.z, px2[mi]) - fmaxf(t.x, px1[mi]), 0.f);
            float h = fmaxf(fminf(t.w, py2[mi]) - fmaxf(t.y, py1[mi]), 0.f);
            float inter = w * h;
            if (__any(inter > 0.f)) {
                float iou = inter / (area_a + areab[mi] - inter);
                if (iou > best[mi]) { best[mi] = iou; bi[mi] = o; }  // strict >: first max
            }
        }
    }
    // ---- per-prior epilogue
    float ll = 0.f, llm = 0.f, cep = 0.f;
    int cp = 0, cp1 = 0;
#pragma unroll
    for (int mi = 0; mi < MULT; ++mi) {
        if (!act[mi]) continue;
        int p = p0 + mi * 256 + tid;
        int ti = bi[mi]; float ov = best[mi];
        if (bms[(p - p0) >> 5] & (1u << (p & 31))) {     // scatter override (<=64/row)
            for (int j = 0; j < O; ++j)
                if (sovp[j] == p) { ti = j; ov = sovv[j] ? 2.0f : best[mi]; break; }
        }
        int conf = 0;
        if (av && ov >= THRESH) conf = (int)lab[ti];      // label is +-1.0 exactly
        float2 c01 = ((const float2*)conf_data)[b * P + p];
        float c0 = c01.x, c1 = c01.y;
        float m = fmaxf(c0, c1);
        float lse = m + logf(expf(c0 - m) + expf(c1 - m));
        bool pos = conf != 0;
        float ce = lse - (pos ? c1 : c0);
        float rv = pos ? 0.f : ce;
        rank[b * P + p] = rv;
        atomicAdd(&lhist[__float_as_uint(rv) >> HSHIFT], 1);
        if (pos) {
            cp++; cep += ce;
            float cx = pr4[mi].x, cy = pr4[mi].y, sw = pr4[mi].z, sh = pr4[mi].w;
            float4 t = t4[ti];
            float gx = ((t.x + t.z) * 0.5f - cx) / (0.1f * sw);
            float gy = ((t.y + t.w) * 0.5f - cy) / (0.1f * sh);
            float gw = logf((t.z - t.x) / sw) / 0.2f;
            float gh = logf((t.w - t.y) / sh) / 0.2f;
            const float* ld = &loc_data[(size_t)(b * P + p) * 4];
            ll += smooth_l1(ld[0] - gx) + smooth_l1(ld[1] - gy) +
                  smooth_l1(ld[2] - gw) + smooth_l1(ld[3] - gh);
            if (conf > 0) {
                cp1++;
                const float* lmd = &landm_data[(size_t)(b * P + p) * 10];
                for (int k5 = 0; k5 < 5; ++k5) {
                    float lx = (lm[ti][k5 * 2 + 0] - cx) / (0.1f * sw);
                    float ly = (lm[ti][k5 * 2 + 1] - cy) / (0.1f * sh);
                    llm += smooth_l1(lmd[k5 * 2 + 0] - lx) + smooth_l1(lmd[k5 * 2 + 1] - ly);
                }
            }
        }
    }
    int wid = tid >> 6, lid = tid & 63;
    float s_ll = wave_sum(ll), s_llm = wave_sum(llm), s_cep = wave_sum(cep);
    int s_cp = wave_sum_i(cp), s_cp1 = wave_sum_i(cp1);
    if (lid == 0) {
        wredf[0][wid] = s_ll; wredf[1][wid] = s_llm; wredf[2][wid] = s_cep;
        wredi[0][wid] = s_cp; wredi[1][wid] = s_cp1;
    }
    __syncthreads();
    if (tid == 0) {
        float ll_t = wredf[0][0] + wredf[0][1] + wredf[0][2] + wredf[0][3];
        float llm_t = wredf[1][0] + wredf[1][1] + wredf[1][2] + wredf[1][3];
        float cep_t = wredf[2][0] + wredf[2][1] + wredf[2][2] + wredf[2][3];
        int cp_t = wredi[0][0] + wredi[0][1] + wredi[0][2] + wredi[0][3];
        int cp1_t = wredi[1][0] + wredi[1][1] + wredi[1][2] + wredi[1][3];
        if (ll_t != 0.f)  atomicAdd(&gsum[0], ll_t);
        if (llm_t != 0.f) atomicAdd(&gsum[1], llm_t);
        if (cep_t != 0.f) atomicAdd(&pos_ce[b], cep_t);
        if (cp_t)  atomicAdd(&num_pos[b], cp_t);
        if (cp1_t) atomicAdd(num_pos1_tot, cp1_t);
    }
    int* gh = hist + (size_t)b * HB;
#pragma unroll
    for (int i = tid; i < HB; i += 256) {
        int c = lhist[i];
        if (c) atomicAdd(&gh[i], c);
    }
}

// ---------------- Kernel E0: per-row coarse-bin selection from hist.
__global__ void kE0_findbin(const int* __restrict__ hist, const int* __restrict__ num_pos,
                            int* __restrict__ binArr, int* __restrict__ kkArr) {
    int b = blockIdx.x;
    const int* h = hist + (size_t)b * HB;
    int k = num_pos[b] * 7;
    if (k > P - 1) k = P - 1;
    __shared__ int chunkSum[256];
    int t = threadIdx.x;
    int cs = 0;
#pragma unroll
    for (int i = 0; i < HB / 256; ++i) cs += h[t * (HB / 256) + i];
    chunkSum[t] = cs;
    __syncthreads();
    if (t == 0) {
        if (k <= 0) { binArr[b] = -1; kkArr[b] = 0; return; }
        int cum = 0, bin = 0, kk = k;
        for (int c = 255; c >= 0; --c) {
            if (cum + chunkSum[c] >= k) {
                for (int i = HB / 256 - 1; i >= 0; --i) {
                    int hv = h[c * (HB / 256) + i];
                    if (cum + hv >= k) { bin = c * (HB / 256) + i; kk = k - cum; goto found; }
                    cum += hv;
                }
            }
            cum += chunkSum[c];
        }
    found:
        binArr[b] = bin; kkArr[b] = kk;
    }
}

// ---------------- Kernel E1: parallel row scan — partial sum of above-bin values +
// candidate gather (LDS compaction, one global reservation per block).
__global__ void kE1_scan(const float* __restrict__ rank, const int* __restrict__ binArr,
                         float* __restrict__ sumgt_part, unsigned* __restrict__ cand,
                         int* __restrict__ cand_cnt) {
    int seg = blockIdx.x % ESPLIT;
    int b = blockIdx.x / ESPLIT;
    int bin = binArr[b];
    if (bin < 0) return;
    const float* r = rank + (size_t)b * P;
    unsigned lo_bound = ((unsigned)(bin + 1)) << HSHIFT;
    __shared__ unsigned lc[PSEG];
    __shared__ int lcnt, gbase;
    __shared__ float wred[4];
    int t = threadIdx.x;
    if (t == 0) lcnt = 0;
    __syncthreads();
    int pend = min((seg + 1) * PSEG, P);
    float sumgt = 0.f;
    for (int p = seg * PSEG + t; p < pend; p += 256) {
        float v = r[p];
        unsigned u = __float_as_uint(v);
        if (u >= lo_bound) sumgt += v;
        else if ((u >> HSHIFT) == (unsigned)bin) {
            int idx = atomicAdd(&lcnt, 1);
            lc[idx] = u;
        }
    }
    __syncthreads();
    if (t == 0 && lcnt > 0) gbase = atomicAdd(&cand_cnt[b], lcnt);
    int wid = t >> 6, lid = t & 63;
    float s = wave_sum(sumgt);
    if (lid == 0) wred[wid] = s;
    __syncthreads();
    int n = lcnt, g0 = (n > 0) ? gbase : 0;
    for (int i = t; i < n; i += 256) {
        int d = g0 + i;
        if (d < CCAP) cand[(size_t)b * CCAP + d] = lc[i];
    }
    if (t == 0) {
        float tot = wred[0] + wred[1] + wred[2] + wred[3];
        if (tot != 0.f) atomicAdd(&sumgt_part[b], tot);
    }
}

// ---------------- Kernel E2: resolve remaining 20 bits over candidate list + final sum.
__global__ void kE2_resolve(const float* __restrict__ rank, const unsigned* __restrict__ cand,
                            const int* __restrict__ cand_cnt, const int* __restrict__ binArr,
                            const int* __restrict__ kkArr, const float* __restrict__ sumgt_part,
                            float* __restrict__ topk) {
    int b = blockIdx.x;
    int bin = binArr[b];
    if (bin < 0) return;                    // topk pre-zeroed
    int m = cand_cnt[b];
    int kk0 = kkArr[b];
    const unsigned* cd = cand + (size_t)b * CCAP;
    const float* r = rank + (size_t)b * P;
    bool useG = (m > CCAP);                 // pathological overflow: rescan row
    __shared__ unsigned lcand[CCAP];
    __shared__ int hist2[256];
    __shared__ int s_bin, s_kk;
    __shared__ float redf[256];
    __shared__ int redi[256];
    int t = threadIdx.x;
    if (!useG)
        for (int i = t; i < m; i += 256) lcand[i] = cd[i];
    __syncthreads();
    unsigned pref = ((unsigned)bin) << HSHIFT;
    unsigned resolved = 0xFFFFFFFFu << HSHIFT;
    int kk = kk0;
    const int shifts[3] = {12, 4, 0};
    const int nbins[3] = {256, 256, 16};
    for (int pass = 0; pass < 3; ++pass) {
        int sh = shifts[pass], nb = nbins[pass];
        for (int i = t; i < nb; i += 256) hist2[i] = 0;
        __syncthreads();
        if (!useG) {
            for (int i = t; i < m; i += 256) {
                unsigned u = lcand[i];
                if ((u & resolved) == pref) atomicAdd(&hist2[(u >> sh) & (nb - 1)], 1);
            }
        } else {
            for (int p = t; p < P; p += 256) {
                unsigned u = __float_as_uint(r[p]);
                if ((u & resolved) == pref) atomicAdd(&hist2[(u >> sh) & (nb - 1)], 1);
            }
        }
        __syncthreads();
        if (t == 0) {
            int cum = 0, d = 0, kn = kk;
            for (int i = nb - 1; i >= 0; --i) {
                if (cum + hist2[i] >= kk) { d = i; kn = kk - cum; break; }
                cum += hist2[i];
            }
            s_bin = d; s_kk = kn;
        }
        __syncthreads();
        pref |= ((unsigned)s_bin) << sh;
        resolved |= (unsigned)(nb - 1) << sh;
        kk = s_kk;
        __syncthreads();
    }
    float tv = __uint_as_float(pref);    // exact k-th largest value
    float sumS = 0.f; int cntS = 0;
    if (!useG) {
        for (int i = t; i < m; i += 256) {
            float v = __uint_as_float(lcand[i]);
            if (v > tv) { sumS += v; cntS++; }
        }
    } else {
        for (int p = t; p < P; p += 256) {
            unsigned u = __float_as_uint(r[p]);
            if ((u >> HSHIFT) == (unsigned)bin) {
                float v = __uint_as_float(u);
                if (v > tv) { sumS += v; cntS++; }
            }
        }
    }
    redf[t] = sumS; redi[t] = cntS; __syncthreads();
    for (int s = 128; s > 0; s >>= 1) {
        if (t < s) { redf[t] += redf[t + s]; redi[t] += redi[t + s]; }
        __syncthreads();
    }
    if (t == 0) topk[b] = sumgt_part[b] + redf[0] + (float)(kk0 - redi[0]) * tv;
}

// ---------------- Kernel F: finalize
__global__ void kF_final(const int* __restrict__ num_pos, const float* __restrict__ pos_ce,
                         const float* __restrict__ topk, const float* __restrict__ gsum,
                         const int* __restrict__ num_pos1_tot, float* __restrict__ out) {
    if (threadIdx.x != 0 || blockIdx.x != 0) return;
    int np = 0; float lc = 0.f;
    for (int b = 0; b < B; ++b) { np += num_pos[b]; lc += pos_ce[b] + topk[b]; }
    float N = fmaxf((float)np, 1.f);
    float N1 = fmaxf((float)(*num_pos1_tot), 1.f);
    out[0] = gsum[0] / N;
    out[1] = lc / N;
    out[2] = gsum[1] / N1;
}

extern "C" void kernel_launch(void* const* d_in, const int* in_sizes, int n_in,
                              void* d_out, int out_size, void* d_ws, size_t ws_size,
                              hipStream_t stream) {
    const float* loc_data   = (const float*)d_in[0];
    const float* conf_data  = (const float*)d_in[1];
    const float* landm_data = (const float*)d_in[2];
    const float* priors     = (const float*)d_in[3];
    const float* targets    = (const float*)d_in[4];
    float* out = (float*)d_out;

    char* ws = (char*)d_ws;
    size_t off = 0;
    auto alloc = [&](size_t bytes) -> void* {
        void* p = ws + off;
        off += (bytes + 255) & ~(size_t)255;
        return p;
    };
    float* rank     = (float*)alloc((size_t)B * P * 4);
    unsigned long long* bp_part = (unsigned long long*)alloc((size_t)B * O * SPLIT * 8);
    unsigned* cand  = (unsigned*)alloc((size_t)B * CCAP * 4);
    unsigned* bitmap = (unsigned*)alloc((size_t)B * BMW * 4);   // zeroed inside kC
    int* ov_p       = (int*)alloc(B * O * 4);
    int* ov_v       = (int*)alloc(B * O * 4);
    int* binArr     = (int*)alloc(B * 4);
    int* kkArr      = (int*)alloc(B * 4);
    // zeroed region: hist + accumulators
    size_t hist_bytes = (size_t)B * HB * 4;
    char* zbase = (char*)alloc(hist_bytes);
    int* hist = (int*)zbase;
    size_t acc_bytes = (size_t)(B * 6 * 4 + 16);
    char* acc = (char*)alloc(acc_bytes);
    int*   any_valid    = (int*)acc;
    int*   num_pos      = (int*)(acc + B * 4);
    float* pos_ce       = (float*)(acc + 2 * B * 4);
    float* topk         = (float*)(acc + 3 * B * 4);
    int*   cand_cnt     = (int*)(acc + 4 * B * 4);
    float* sumgt_part   = (float*)(acc + 5 * B * 4);
    float* gsum         = (float*)(acc + 6 * B * 4);
    int*   num_pos1_tot = (int*)(acc + 6 * B * 4 + 8);
    size_t zlen = (size_t)(acc - zbase) + acc_bytes;

    hipMemsetAsync(zbase, 0, zlen, stream);

    kB_best_prior<<<dim3(B * (O / TG) * SPLIT), dim3(256), 0, stream>>>(priors, targets, bp_part);
    kC_scatter<<<dim3(B), dim3(64), 0, stream>>>(bp_part, bitmap, ov_p, ov_v, any_valid);
    kD_main<<<dim3(B * NB2), dim3(256), 0, stream>>>(loc_data, conf_data, landm_data, priors,
                                                     targets, bitmap, ov_p, ov_v, any_valid,
                                                     rank, hist, num_pos, pos_ce, gsum,
                                                     num_pos1_tot);
    kE0_findbin<<<dim3(B), dim3(256), 0, stream>>>(hist, num_pos, binArr, kkArr);
    kE1_scan<<<dim3(B * ESPLIT), dim3(256), 0, stream>>>(rank, binArr, sumgt_part, cand, cand_cnt);
    kE2_resolve<<<dim3(B), dim3(256), 0, stream>>>(rank, cand, cand_cnt, binArr, kkArr,
                                                   sumgt_part, topk);
    kF_final<<<dim3(1), dim3(64), 0, stream>>>(num_pos, pos_ce, topk, gsum, num_pos1_tot, out);
}

// Round 8
// 248.913 us; speedup vs baseline: 1.5529x; 1.0673x over previous
//
#include <hip/hip_runtime.h>
#include <math.h>

#define B 64
#define P 16800
#define O 64
#define THRESH 0.35f
#define VALID_T 0.2f
#define HB 2048            // coarse hist bins = top 11 bits of float bits (rank >= 0)
#define HSHIFT 21
#define ESPLIT 16          // row splits in kE1
#define PSEG ((P + ESPLIT - 1) / ESPLIT)   // 1050
#define CCAP 4096          // per-row global candidate capacity
#define MULT 2             // priors per thread in kD1 (registers)
#define CHB (MULT * 256)   // 512 priors per kD1 block
#define NB2 ((P + CHB - 1) / CHB)          // 33 blocks per row

__device__ __forceinline__ float smooth_l1(float x) {
    float ax = fabsf(x);
    return ax < 1.f ? 0.5f * ax * ax : ax - 0.5f;
}
__device__ __forceinline__ float wave_sum(float v) {
#pragma unroll
    for (int s = 32; s > 0; s >>= 1) v += __shfl_down(v, s, 64);
    return v;
}
__device__ __forceinline__ int wave_sum_i(int v) {
#pragma unroll
    for (int s = 32; s > 0; s >>= 1) v += __shfl_down(v, s, 64);
    return v;
}
__device__ __forceinline__ float wave_min(float v) {
#pragma unroll
    for (int s = 32; s > 0; s >>= 1) v = fminf(v, __shfl_xor(v, s, 64));
    return v;
}
__device__ __forceinline__ float wave_max(float v) {
#pragma unroll
    for (int s = 32; s > 0; s >>= 1) v = fmaxf(v, __shfl_xor(v, s, 64));
    return v;
}
// shared IoU helper: used by BOTH kD1 and kC2 so recomputation is bit-identical
__device__ __forceinline__ float iou_pt(float4 t, float area_a,
                                        float px1, float py1, float px2, float py2,
                                        float area_b) {
    float w = fmaxf(fminf(t.z, px2) - fmaxf(t.x, px1), 0.f);
    float h = fmaxf(fminf(t.w, py2) - fmaxf(t.y, py1), 0.f);
    float inter = w * h;
    return inter / (area_a + area_b - inter);
}

// ---------------- Kernel D1 (fused kA+kB+kD, no-override epilogue):
// per-prior best-truth argmax + per-truth per-block best-prior partials +
// CE/rank/losses assuming no scatter override (kC2 fixes the <=64/row later).
// any_valid is provably redundant (no valid truth => all iou < 0.2 => conf==0).
__global__ void __launch_bounds__(256) kD1_main(
        const float* __restrict__ loc_data, const float* __restrict__ conf_data,
        const float* __restrict__ landm_data, const float* __restrict__ priors,
        const float* __restrict__ targets,
        float* __restrict__ rank, int* __restrict__ hist,
        unsigned long long* __restrict__ bp_part,
        int* __restrict__ num_pos, float* __restrict__ pos_ce,
        float* __restrict__ gsum, int* __restrict__ num_pos1_tot) {
    int blk = blockIdx.x % NB2;
    int b = blockIdx.x / NB2;
    int p0 = blk * CHB;
    __shared__ float4 t4[O];
    __shared__ float ta[O], lab[O];
    __shared__ float lm[O][10];
    __shared__ unsigned long long skey[O];
    __shared__ int lhist[HB];
    __shared__ float wredf[3][4];
    __shared__ int wredi[2][4];
    int tid = threadIdx.x;
    if (tid < O) {
        const float* t = &targets[(b * O + tid) * 15];
        float a0 = t[0], a1 = t[1], a2 = t[2], a3 = t[3];
        t4[tid] = make_float4(a0, a1, a2, a3);
        ta[tid] = (a2 - a0) * (a3 - a1);
        lab[tid] = t[14];
        // init: iou=0, p=p0 (block's smallest p) -> cross-block reduce gives ref's
        // argmax-of-zeros = index 0 semantics
        skey[tid] = (unsigned long long)(0xFFFFFFFFu - (unsigned)p0);
    }
    for (int i = tid; i < O * 10; i += 256)
        lm[i / 10][i % 10] = targets[b * O * 15 + (i / 10) * 15 + 4 + (i % 10)];
    for (int i = tid; i < HB; i += 256) lhist[i] = 0;
    __syncthreads();
    // MULT priors in registers + per-wave bbox
    float px1[MULT], py1[MULT], px2[MULT], py2[MULT], areab[MULT];
    float4 pr4[MULT];
    float best[MULT]; int bi[MULT]; bool act[MULT];
    float bx1 = 1e30f, by1 = 1e30f, bx2 = -1e30f, by2 = -1e30f;
#pragma unroll
    for (int mi = 0; mi < MULT; ++mi) {
        int p = p0 + mi * 256 + tid;
        act[mi] = (p < P);
        int pc = act[mi] ? p : (P - 1);
        float4 q = ((const float4*)priors)[pc];
        pr4[mi] = q;
        px1[mi] = q.x - q.z * 0.5f; py1[mi] = q.y - q.w * 0.5f;
        px2[mi] = q.x + q.z * 0.5f; py2[mi] = q.y + q.w * 0.5f;
        areab[mi] = (px2[mi] - px1[mi]) * (py2[mi] - py1[mi]);
        bx1 = fminf(bx1, px1[mi]); by1 = fminf(by1, py1[mi]);
        bx2 = fmaxf(bx2, px2[mi]); by2 = fmaxf(by2, py2[mi]);
        best[mi] = 0.f; bi[mi] = 0;
    }
    bx1 = wave_min(bx1); by1 = wave_min(by1);
    bx2 = wave_max(bx2); by2 = wave_max(by2);
    // o outer; wave-bbox skip exact (skipped => iou==0 can't beat best>=0 or skey init)
    for (int o = 0; o < O; ++o) {
        float4 t = t4[o];
        float w0 = fminf(t.z, bx2) - fmaxf(t.x, bx1);
        float h0 = fminf(t.w, by2) - fmaxf(t.y, by1);
        if (w0 <= 0.f || h0 <= 0.f) continue;   // wave-uniform
        float area_a = ta[o];
        unsigned long long km = 0ULL;
#pragma unroll
        for (int mi = 0; mi < MULT; ++mi) {
            float iou = iou_pt(t, area_a, px1[mi], py1[mi], px2[mi], py2[mi], areab[mi]);
            if (iou > best[mi]) { best[mi] = iou; bi[mi] = o; }   // strict >: first max
            if (act[mi]) {
                unsigned long long kk = ((unsigned long long)__float_as_uint(iou) << 32)
                                      | (unsigned)(0xFFFFFFFFu - (unsigned)(p0 + mi * 256 + tid));
                if (kk > km) km = kk;
            }
        }
#pragma unroll
        for (int s = 32; s > 0; s >>= 1) {
            unsigned long long om = __shfl_xor(km, s, 64);
            if (om > km) km = om;
        }
        if ((tid & 63) == 0) atomicMax(&skey[o], km);
    }
    // per-prior epilogue (no override, no any_valid)
    float ll = 0.f, llm = 0.f, cep = 0.f;
    int cp = 0, cp1 = 0;
#pragma unroll
    for (int mi = 0; mi < MULT; ++mi) {
        if (!act[mi]) continue;
        int p = p0 + mi * 256 + tid;
        int conf = (best[mi] >= THRESH) ? (int)lab[bi[mi]] : 0;   // label +-1.0 exact
        float2 c01 = ((const float2*)conf_data)[b * P + p];
        float c0 = c01.x, c1 = c01.y;
        float m = fmaxf(c0, c1);
        float lse = m + logf(expf(c0 - m) + expf(c1 - m));
        bool pos = conf != 0;
        float ce = lse - (pos ? c1 : c0);
        float rv = pos ? 0.f : ce;
        rank[(size_t)b * P + p] = rv;
        atomicAdd(&lhist[__float_as_uint(rv) >> HSHIFT], 1);
        if (pos) {
            cp++; cep += ce;
            int ti = bi[mi];
            float cx = pr4[mi].x, cy = pr4[mi].y, sw = pr4[mi].z, sh = pr4[mi].w;
            float4 t = t4[ti];
            float gx = ((t.x + t.z) * 0.5f - cx) / (0.1f * sw);
            float gy = ((t.y + t.w) * 0.5f - cy) / (0.1f * sh);
            float gw = logf((t.z - t.x) / sw) / 0.2f;
            float gh = logf((t.w - t.y) / sh) / 0.2f;
            const float* ld = &loc_data[(size_t)(b * P + p) * 4];
            ll += smooth_l1(ld[0] - gx) + smooth_l1(ld[1] - gy) +
                  smooth_l1(ld[2] - gw) + smooth_l1(ld[3] - gh);
            if (conf > 0) {
                cp1++;
                const float* lmd = &landm_data[(size_t)(b * P + p) * 10];
                for (int k5 = 0; k5 < 5; ++k5) {
                    float lx = (lm[ti][k5 * 2 + 0] - cx) / (0.1f * sw);
                    float ly = (lm[ti][k5 * 2 + 1] - cy) / (0.1f * sh);
                    llm += smooth_l1(lmd[k5 * 2 + 0] - lx) + smooth_l1(lmd[k5 * 2 + 1] - ly);
                }
            }
        }
    }
    int wid = tid >> 6, lid = tid & 63;
    float s_ll = wave_sum(ll), s_llm = wave_sum(llm), s_cep = wave_sum(cep);
    int s_cp = wave_sum_i(cp), s_cp1 = wave_sum_i(cp1);
    if (lid == 0) {
        wredf[0][wid] = s_ll; wredf[1][wid] = s_llm; wredf[2][wid] = s_cep;
        wredi[0][wid] = s_cp; wredi[1][wid] = s_cp1;
    }
    __syncthreads();   // also orders all skey atomicMax before flush below
    if (tid == 0) {
        float ll_t = wredf[0][0] + wredf[0][1] + wredf[0][2] + wredf[0][3];
        float llm_t = wredf[1][0] + wredf[1][1] + wredf[1][2] + wredf[1][3];
        float cep_t = wredf[2][0] + wredf[2][1] + wredf[2][2] + wredf[2][3];
        int cp_t = wredi[0][0] + wredi[0][1] + wredi[0][2] + wredi[0][3];
        int cp1_t = wredi[1][0] + wredi[1][1] + wredi[1][2] + wredi[1][3];
        if (ll_t != 0.f)  atomicAdd(&gsum[0], ll_t);
        if (llm_t != 0.f) atomicAdd(&gsum[1], llm_t);
        if (cep_t != 0.f) atomicAdd(&pos_ce[b], cep_t);
        if (cp_t)  atomicAdd(&num_pos[b], cp_t);
        if (cp1_t) atomicAdd(num_pos1_tot, cp1_t);
    }
    if (tid < O) bp_part[((size_t)b * O + tid) * NB2 + blk] = skey[tid];
    int* gh = hist + (size_t)b * HB;
#pragma unroll
    for (int i = tid; i < HB; i += 256) {
        int c = lhist[i];
        if (c) atomicAdd(&gh[i], c);
    }
}

// ---------------- Kernel C2 (fixup): reduce per-truth partials, dedup (last j wins),
// recompute the <=64 overridden priors exactly, apply atomic deltas.
__global__ void kC2_fixup(const float* __restrict__ priors, const float* __restrict__ targets,
                          const float* __restrict__ loc_data, const float* __restrict__ conf_data,
                          const float* __restrict__ landm_data,
                          const unsigned long long* __restrict__ bp_part,
                          float* __restrict__ rank, int* __restrict__ hist,
                          int* __restrict__ num_pos, float* __restrict__ pos_ce,
                          float* __restrict__ gsum, int* __restrict__ num_pos1_tot,
                          int* __restrict__ np_tot) {
    int b = blockIdx.x;
    int j = threadIdx.x;               // 0..63, one truth per lane
    __shared__ float4 t4[O];
    __shared__ float ta[O], lab[O];
    __shared__ int sp[O];
    const float* tt = &targets[(b * O + j) * 15];
    float4 tj = make_float4(tt[0], tt[1], tt[2], tt[3]);
    t4[j] = tj;
    ta[j] = (tj.z - tj.x) * (tj.w - tj.y);
    lab[j] = tt[14];
    const unsigned long long* part = &bp_part[((size_t)b * O + j) * NB2];
    unsigned long long k = part[0];
    for (int s = 1; s < NB2; ++s) { unsigned long long kw = part[s]; if (kw > k) k = kw; }
    int p = (int)(0xFFFFFFFFu - (unsigned)(k & 0xFFFFFFFFu));
    float iou = __uint_as_float((unsigned)(k >> 32));
    int v = (iou >= VALID_T) ? 1 : 0;
    sp[j] = p;
    __syncthreads();
    bool winner = true;                // last j with this p wins (numpy scatter)
    for (int jj = j + 1; jj < O; ++jj)
        if (sp[jj] == p) { winner = false; break; }
    if (winner) {
        float4 q = ((const float4*)priors)[p];
        float px1 = q.x - q.z * 0.5f, py1 = q.y - q.w * 0.5f;
        float px2 = q.x + q.z * 0.5f, py2 = q.y + q.w * 0.5f;
        float areab = (px2 - px1) * (py2 - py1);
        float best = 0.f; int bi = 0;
        for (int o = 0; o < O; ++o) {
            float io = iou_pt(t4[o], ta[o], px1, py1, px2, py2, areab);
            if (io > best) { best = io; bi = o; }
        }
        float ov_new = v ? 2.0f : best;
        int conf_old = (best >= THRESH) ? (int)lab[bi] : 0;
        int conf_new = (ov_new >= THRESH) ? (int)lab[j] : 0;
        float2 c01 = ((const float2*)conf_data)[b * P + p];
        float c0 = c01.x, c1 = c01.y, m = fmaxf(c0, c1);
        float lse = m + logf(expf(c0 - m) + expf(c1 - m));
        bool po = conf_old != 0, pn = conf_new != 0;
        float ceo = lse - (po ? c1 : c0), cen = lse - (pn ? c1 : c0);
        float rvo = po ? 0.f : ceo, rvn = pn ? 0.f : cen;
        if (__float_as_uint(rvo) != __float_as_uint(rvn)) {
            rank[(size_t)b * P + p] = rvn;
            int bo = __float_as_uint(rvo) >> HSHIFT, bn = __float_as_uint(rvn) >> HSHIFT;
            if (bo != bn) {
                atomicAdd(&hist[(size_t)b * HB + bn], 1);
                atomicAdd(&hist[(size_t)b * HB + bo], -1);
            }
        }
        const float* ld = &loc_data[(size_t)(b * P + p) * 4];
        auto enc_ll = [&](int ti) -> float {     // identical float ops to kD1 epilogue
            float4 t = t4[ti];
            float gx = ((t.x + t.z) * 0.5f - q.x) / (0.1f * q.z);
            float gy = ((t.y + t.w) * 0.5f - q.y) / (0.1f * q.w);
            float gw = logf((t.z - t.x) / q.z) / 0.2f;
            float gh = logf((t.w - t.y) / q.w) / 0.2f;
            return smooth_l1(ld[0] - gx) + smooth_l1(ld[1] - gy) +
                   smooth_l1(ld[2] - gw) + smooth_l1(ld[3] - gh);
        };
        float dll = 0.f;
        if (po) dll -= enc_ll(bi);
        if (pn) dll += enc_ll(j);
        if (dll != 0.f) atomicAdd(&gsum[0], dll);
        float dce = (pn ? cen : 0.f) - (po ? ceo : 0.f);
        if (dce != 0.f) atomicAdd(&pos_ce[b], dce);
        int dnp = (int)pn - (int)po;
        if (dnp) atomicAdd(&num_pos[b], dnp);
        const float* lmd = &landm_data[(size_t)(b * P + p) * 10];
        auto enc_lm = [&](int ti) -> float {
            const float* lmt = &targets[(b * O + ti) * 15 + 4];
            float sum = 0.f;
            for (int k5 = 0; k5 < 5; ++k5) {
                float lx = (lmt[k5 * 2 + 0] - q.x) / (0.1f * q.z);
                float ly = (lmt[k5 * 2 + 1] - q.y) / (0.1f * q.w);
                sum += smooth_l1(lmd[k5 * 2 + 0] - lx) + smooth_l1(lmd[k5 * 2 + 1] - ly);
            }
            return sum;
        };
        float dllm = 0.f;
        if (conf_old > 0) dllm -= enc_lm(bi);
        if (conf_new > 0) dllm += enc_lm(j);
        if (dllm != 0.f) atomicAdd(&gsum[1], dllm);
        int dn1 = (int)(conf_new > 0) - (int)(conf_old > 0);
        if (dn1) atomicAdd(num_pos1_tot, dn1);
    }
    __threadfence();
    __syncthreads();
    if (j == 0) {
        int npb = atomicAdd(&num_pos[b], 0);   // atomic read: includes own fixups
        atomicAdd(np_tot, npb);
    }
}

// ---------------- Kernel E0: per-row coarse-bin selection from hist.
__global__ void kE0_findbin(const int* __restrict__ hist, const int* __restrict__ num_pos,
                            int* __restrict__ binArr, int* __restrict__ kkArr) {
    int b = blockIdx.x;
    const int* h = hist + (size_t)b * HB;
    int k = num_pos[b] * 7;
    if (k > P - 1) k = P - 1;
    __shared__ int chunkSum[256];
    int t = threadIdx.x;
    int cs = 0;
#pragma unroll
    for (int i = 0; i < HB / 256; ++i) cs += h[t * (HB / 256) + i];
    chunkSum[t] = cs;
    __syncthreads();
    if (t == 0) {
        if (k <= 0) { binArr[b] = -1; kkArr[b] = 0; return; }
        int cum = 0, bin = 0, kk = k;
        for (int c = 255; c >= 0; --c) {
            if (cum + chunkSum[c] >= k) {
                for (int i = HB / 256 - 1; i >= 0; --i) {
                    int hv = h[c * (HB / 256) + i];
                    if (cum + hv >= k) { bin = c * (HB / 256) + i; kk = k - cum; goto found; }
                    cum += hv;
                }
            }
            cum += chunkSum[c];
        }
    found:
        binArr[b] = bin; kkArr[b] = kk;
    }
}

// ---------------- Kernel E1: parallel row scan — partial above-bin sum + candidate gather.
__global__ void kE1_scan(const float* __restrict__ rank, const int* __restrict__ binArr,
                         float* __restrict__ sumgt_part, unsigned* __restrict__ cand,
                         int* __restrict__ cand_cnt) {
    int seg = blockIdx.x % ESPLIT;
    int b = blockIdx.x / ESPLIT;
    int bin = binArr[b];
    if (bin < 0) return;
    const float* r = rank + (size_t)b * P;
    unsigned lo_bound = ((unsigned)(bin + 1)) << HSHIFT;
    __shared__ unsigned lc[PSEG];
    __shared__ int lcnt, gbase;
    __shared__ float wred[4];
    int t = threadIdx.x;
    if (t == 0) lcnt = 0;
    __syncthreads();
    int pend = min((seg + 1) * PSEG, P);
    float sumgt = 0.f;
    for (int p = seg * PSEG + t; p < pend; p += 256) {
        float v = r[p];
        unsigned u = __float_as_uint(v);
        if (u >= lo_bound) sumgt += v;
        else if ((u >> HSHIFT) == (unsigned)bin) {
            int idx = atomicAdd(&lcnt, 1);
            lc[idx] = u;
        }
    }
    __syncthreads();
    if (t == 0 && lcnt > 0) gbase = atomicAdd(&cand_cnt[b], lcnt);
    int wid = t >> 6, lid = t & 63;
    float s = wave_sum(sumgt);
    if (lid == 0) wred[wid] = s;
    __syncthreads();
    int n = lcnt, g0 = (n > 0) ? gbase : 0;
    for (int i = t; i < n; i += 256) {
        int d = g0 + i;
        if (d < CCAP) cand[(size_t)b * CCAP + d] = lc[i];
    }
    if (t == 0) {
        float tot = wred[0] + wred[1] + wred[2] + wred[3];
        if (tot != 0.f) atomicAdd(&sumgt_part[b], tot);
    }
}

// ---------------- Kernel E2: resolve remaining 21 bits + final sum; LAST block writes out[3].
__global__ void kE2_resolve(const float* __restrict__ rank, const unsigned* __restrict__ cand,
                            const int* __restrict__ cand_cnt, const int* __restrict__ binArr,
                            const int* __restrict__ kkArr, const float* __restrict__ sumgt_part,
                            const float* __restrict__ pos_ce, float* __restrict__ gsum,
                            int* __restrict__ np_tot, int* __restrict__ np1_tot,
                            float* __restrict__ lossc_tot, int* __restrict__ done,
                            float* __restrict__ out) {
    int b = blockIdx.x;
    int bin = binArr[b];
    int t = threadIdx.x;
    __shared__ unsigned lcand[CCAP];
    __shared__ int hist2[256];
    __shared__ int s_bin, s_kk;
    __shared__ float redf[256];
    __shared__ int redi[256];
    float topk_b = 0.f;
    if (bin >= 0) {                      // block-uniform branch: __syncthreads safe
        int m = cand_cnt[b];
        int kk0 = kkArr[b];
        const unsigned* cd = cand + (size_t)b * CCAP;
        const float* r = rank + (size_t)b * P;
        bool useG = (m > CCAP);          // pathological overflow: rescan row
        if (!useG)
            for (int i = t; i < m; i += 256) lcand[i] = cd[i];
        __syncthreads();
        unsigned pref = ((unsigned)bin) << HSHIFT;
        unsigned resolved = 0xFFFFFFFFu << HSHIFT;
        int kk = kk0;
        const int shifts[3] = {13, 5, 0};
        const int nbins[3] = {256, 256, 32};
        for (int pass = 0; pass < 3; ++pass) {
            int sh = shifts[pass], nb = nbins[pass];
            for (int i = t; i < nb; i += 256) hist2[i] = 0;
            __syncthreads();
            if (!useG) {
                for (int i = t; i < m; i += 256) {
                    unsigned u = lcand[i];
                    if ((u & resolved) == pref) atomicAdd(&hist2[(u >> sh) & (nb - 1)], 1);
                }
            } else {
                for (int p = t; p < P; p += 256) {
                    unsigned u = __float_as_uint(r[p]);
                    if ((u & resolved) == pref) atomicAdd(&hist2[(u >> sh) & (nb - 1)], 1);
                }
            }
            __syncthreads();
            if (t == 0) {
                int cum = 0, d = 0, kn = kk;
                for (int i = nb - 1; i >= 0; --i) {
                    if (cum + hist2[i] >= kk) { d = i; kn = kk - cum; break; }
                    cum += hist2[i];
                }
                s_bin = d; s_kk = kn;
            }
            __syncthreads();
            pref |= ((unsigned)s_bin) << sh;
            resolved |= (unsigned)(nb - 1) << sh;
            kk = s_kk;
            __syncthreads();
        }
        float tv = __uint_as_float(pref);    // exact k-th largest value
        float sumS = 0.f; int cntS = 0;
        if (!useG) {
            for (int i = t; i < m; i += 256) {
                float v = __uint_as_float(lcand[i]);
                if (v > tv) { sumS += v; cntS++; }
            }
        } else {
            for (int p = t; p < P; p += 256) {
                unsigned u = __float_as_uint(r[p]);
                if ((u >> HSHIFT) == (unsigned)bin) {
                    float v = __uint_as_float(u);
                    if (v > tv) { sumS += v; cntS++; }
                }
            }
        }
        redf[t] = sumS; redi[t] = cntS; __syncthreads();
        for (int s = 128; s > 0; s >>= 1) {
            if (t < s) { redf[t] += redf[t + s]; redi[t] += redi[t + s]; }
            __syncthreads();
        }
        if (t == 0) topk_b = sumgt_part[b] + redf[0] + (float)(kk0 - redi[0]) * tv;
    }
    if (t == 0) {
        atomicAdd(lossc_tot, pos_ce[b] + topk_b);
        __threadfence();
        int old = atomicAdd(done, 1);
        if (old == B - 1) {              // last block finalizes (atomic reads: L2-fresh)
            float g0 = atomicAdd(&gsum[0], 0.f);
            float g1 = atomicAdd(&gsum[1], 0.f);
            float lc = atomicAdd(lossc_tot, 0.f);
            int np = atomicAdd(np_tot, 0);
            int n1 = atomicAdd(np1_tot, 0);
            float N = fmaxf((float)np, 1.f);
            float N1 = fmaxf((float)n1, 1.f);
            out[0] = g0 / N;
            out[1] = lc / N;
            out[2] = g1 / N1;
        }
    }
}

extern "C" void kernel_launch(void* const* d_in, const int* in_sizes, int n_in,
                              void* d_out, int out_size, void* d_ws, size_t ws_size,
                              hipStream_t stream) {
    const float* loc_data   = (const float*)d_in[0];
    const float* conf_data  = (const float*)d_in[1];
    const float* landm_data = (const float*)d_in[2];
    const float* priors     = (const float*)d_in[3];
    const float* targets    = (const float*)d_in[4];
    float* out = (float*)d_out;

    char* ws = (char*)d_ws;
    size_t off = 0;
    auto alloc = [&](size_t bytes) -> void* {
        void* p = ws + off;
        off += (bytes + 255) & ~(size_t)255;
        return p;
    };
    float* rank     = (float*)alloc((size_t)B * P * 4);
    unsigned long long* bp_part = (unsigned long long*)alloc((size_t)B * O * NB2 * 8);
    unsigned* cand  = (unsigned*)alloc((size_t)B * CCAP * 4);
    int* binArr     = (int*)alloc(B * 4);
    int* kkArr      = (int*)alloc(B * 4);
    // zeroed region: hist + accumulators
    size_t hist_bytes = (size_t)B * HB * 4;
    char* zbase = (char*)alloc(hist_bytes);
    int* hist = (int*)zbase;
    size_t acc_bytes = (size_t)(B * 4 * 4 + 64);
    char* acc = (char*)alloc(acc_bytes);
    int*   num_pos      = (int*)acc;
    float* pos_ce       = (float*)(acc + B * 4);
    int*   cand_cnt     = (int*)(acc + 2 * B * 4);
    float* sumgt_part   = (float*)(acc + 3 * B * 4);
    float* gsum         = (float*)(acc + 4 * B * 4);       // 2 floats
    int*   np1_tot      = (int*)(acc + 4 * B * 4 + 8);
    int*   np_tot       = (int*)(acc + 4 * B * 4 + 12);
    float* lossc_tot    = (float*)(acc + 4 * B * 4 + 16);
    int*   done         = (int*)(acc + 4 * B * 4 + 20);
    size_t zlen = (size_t)(acc - zbase) + acc_bytes;

    hipMemsetAsync(zbase, 0, zlen, stream);

    kD1_main<<<dim3(B * NB2), dim3(256), 0, stream>>>(loc_data, conf_data, landm_data, priors,
                                                      targets, rank, hist, bp_part,
                                                      num_pos, pos_ce, gsum, np1_tot);
    kC2_fixup<<<dim3(B), dim3(64), 0, stream>>>(priors, targets, loc_data, conf_data, landm_data,
                                                bp_part, rank, hist, num_pos, pos_ce, gsum,
                                                np1_tot, np_tot);
    kE0_findbin<<<dim3(B), dim3(256), 0, stream>>>(hist, num_pos, binArr, kkArr);
    kE1_scan<<<dim3(B * ESPLIT), dim3(256), 0, stream>>>(rank, binArr, sumgt_part, cand, cand_cnt);
    kE2_resolve<<<dim3(B), dim3(256), 0, stream>>>(rank, cand, cand_cnt, binArr, kkArr,
                                                   sumgt_part, pos_ce, gsum, np_tot, np1_tot,
                                                   lossc_tot, done, out);
}

// Round 9
// 236.715 us; speedup vs baseline: 1.6329x; 1.0515x over previous
//
#include <hip/hip_runtime.h>
#include <math.h>

#define B 64
#define P 16800
#define O 64
#define THRESH 0.35f
#define VALID_T 0.2f
#define HB 2048            // coarse hist bins = top 11 bits of float bits (rank >= 0)
#define HSHIFT 21
#define ESPLIT 16          // row splits in kE1
#define PSEG ((P + ESPLIT - 1) / ESPLIT)   // 1050
#define CCAP 4096          // per-row global candidate capacity
#define MULT 2             // priors per thread in kD1 (registers)
#define CHB (MULT * 256)   // 512 priors per kD1 block
#define NB2 ((P + CHB - 1) / CHB)          // 33 blocks per row

__device__ __forceinline__ float smooth_l1(float x) {
    float ax = fabsf(x);
    return ax < 1.f ? 0.5f * ax * ax : ax - 0.5f;
}
__device__ __forceinline__ float wave_sum(float v) {
#pragma unroll
    for (int s = 32; s > 0; s >>= 1) v += __shfl_down(v, s, 64);
    return v;
}
__device__ __forceinline__ int wave_sum_i(int v) {
#pragma unroll
    for (int s = 32; s > 0; s >>= 1) v += __shfl_down(v, s, 64);
    return v;
}
__device__ __forceinline__ float wave_min(float v) {
#pragma unroll
    for (int s = 32; s > 0; s >>= 1) v = fminf(v, __shfl_xor(v, s, 64));
    return v;
}
__device__ __forceinline__ float wave_max(float v) {
#pragma unroll
    for (int s = 32; s > 0; s >>= 1) v = fmaxf(v, __shfl_xor(v, s, 64));
    return v;
}
// shared IoU helper: used by kB2, kD1 and kC2 so recomputation is bit-identical
__device__ __forceinline__ float iou_pt(float4 t, float area_a,
                                        float px1, float py1, float px2, float py2,
                                        float area_b) {
    float w = fmaxf(fminf(t.z, px2) - fmaxf(t.x, px1), 0.f);
    float h = fmaxf(fminf(t.w, py2) - fmaxf(t.y, py1), 0.f);
    float inter = w * h;
    return inter / (area_a + area_b - inter);
}

// ---------------- Kernel B2: per-truth best prior via grid-pruned candidates.
// Priors form 6 contiguous (level,size) blocks of a regular grid; only cells whose
// prior box can intersect the truth are enumerated (superset via +-1 cell margin).
// Excluded priors have iou==0 exactly and cannot beat the (iou=0,p=0) init key.
__global__ void __launch_bounds__(64) kB2_best_prior(
        const float* __restrict__ priors, const float* __restrict__ targets,
        unsigned long long* __restrict__ bp_final) {
    int o = blockIdx.x % O;
    int b = blockIdx.x / O;
    const float* tt = &targets[(b * O + o) * 15];
    float tx1 = tt[0], ty1 = tt[1], tx2 = tt[2], ty2 = tt[3];
    float area_a = (tx2 - tx1) * (ty2 - ty1);
    float4 tb = make_float4(tx1, ty1, tx2, ty2);
    unsigned long long key = (unsigned long long)0xFFFFFFFFu;   // iou=0, p=0 fallback
    const int fs[6]   = {80, 80, 40, 40, 20, 20};
    const int ms[6]   = {16, 32, 64, 128, 256, 512};
    const int base[6] = {0, 6400, 12800, 14400, 16000, 16400};
#pragma unroll
    for (int c = 0; c < 6; ++c) {
        int f = fs[c];
        float inv = (float)f;                         // 640/step == f
        float h = (float)ms[c] * (0.5f / 640.f);
        int j0 = (int)floorf((tx1 - h) * inv - 0.5f) - 1; if (j0 < 0) j0 = 0;
        int j1 = (int)ceilf((tx2 + h) * inv - 0.5f) + 1;  if (j1 > f - 1) j1 = f - 1;
        int i0 = (int)floorf((ty1 - h) * inv - 0.5f) - 1; if (i0 < 0) i0 = 0;
        int i1 = (int)ceilf((ty2 + h) * inv - 0.5f) + 1;  if (i1 > f - 1) i1 = f - 1;
        if (j1 < j0 || i1 < i0) continue;
        int nj = j1 - j0 + 1;
        int n = (i1 - i0 + 1) * nj;
        for (int idx = threadIdx.x; idx < n; idx += 64) {
            int ii = i0 + idx / nj, jj = j0 + idx % nj;
            int p = base[c] + ii * f + jj;
            float4 q = ((const float4*)priors)[p];
            float px1 = q.x - q.z * 0.5f, py1 = q.y - q.w * 0.5f;
            float px2 = q.x + q.z * 0.5f, py2 = q.y + q.w * 0.5f;
            float areab = (px2 - px1) * (py2 - py1);
            float iou = iou_pt(tb, area_a, px1, py1, px2, py2, areab);
            unsigned long long kk = ((unsigned long long)__float_as_uint(iou) << 32)
                                  | (unsigned)(0xFFFFFFFFu - (unsigned)p);
            if (kk > key) key = kk;                   // ties -> smaller p (ref argmax)
        }
    }
#pragma unroll
    for (int s = 32; s > 0; s >>= 1) {
        unsigned long long om = __shfl_xor(key, s, 64);
        if (om > key) key = om;
    }
    if (threadIdx.x == 0) bp_final[b * O + o] = key;
}

// ---------------- Kernel D1 (fused kA+kD, no-override epilogue, active-truth list):
// block bbox prunes the truth set ONCE per block; waves iterate only listed truths.
__global__ void __launch_bounds__(256) kD1_main(
        const float* __restrict__ loc_data, const float* __restrict__ conf_data,
        const float* __restrict__ landm_data, const float* __restrict__ priors,
        const float* __restrict__ targets,
        float* __restrict__ rank, int* __restrict__ hist,
        int* __restrict__ num_pos, float* __restrict__ pos_ce,
        float* __restrict__ gsum, int* __restrict__ np1_tot) {
    int blk = blockIdx.x % NB2;
    int b = blockIdx.x / NB2;
    int p0 = blk * CHB;
    __shared__ float4 t4[O];
    __shared__ float ta[O], lab[O];
    __shared__ float lm[O][10];
    __shared__ int lhist[HB];
    __shared__ float4 wbb[4];
    __shared__ int alist[O];
    __shared__ int s_cnt;
    __shared__ float wredf[3][4];
    __shared__ int wredi[2][4];
    int tid = threadIdx.x;
    if (tid < O) {
        const float* t = &targets[(b * O + tid) * 15];
        float a0 = t[0], a1 = t[1], a2 = t[2], a3 = t[3];
        t4[tid] = make_float4(a0, a1, a2, a3);
        ta[tid] = (a2 - a0) * (a3 - a1);
        lab[tid] = t[14];
    }
    for (int i = tid; i < O * 10; i += 256)
        lm[i / 10][i % 10] = targets[b * O * 15 + (i / 10) * 15 + 4 + (i % 10)];
    for (int i = tid; i < HB; i += 256) lhist[i] = 0;
    // MULT priors in registers + per-wave bbox
    float px1[MULT], py1[MULT], px2[MULT], py2[MULT], areab[MULT];
    float4 pr4[MULT];
    float best[MULT]; int bi[MULT]; bool act[MULT];
    float bx1 = 1e30f, by1 = 1e30f, bx2 = -1e30f, by2 = -1e30f;
#pragma unroll
    for (int mi = 0; mi < MULT; ++mi) {
        int p = p0 + mi * 256 + tid;
        act[mi] = (p < P);
        int pc = act[mi] ? p : (P - 1);
        float4 q = ((const float4*)priors)[pc];
        pr4[mi] = q;
        px1[mi] = q.x - q.z * 0.5f; py1[mi] = q.y - q.w * 0.5f;
        px2[mi] = q.x + q.z * 0.5f; py2[mi] = q.y + q.w * 0.5f;
        areab[mi] = (px2[mi] - px1[mi]) * (py2[mi] - py1[mi]);
        bx1 = fminf(bx1, px1[mi]); by1 = fminf(by1, py1[mi]);
        bx2 = fmaxf(bx2, px2[mi]); by2 = fmaxf(by2, py2[mi]);
        best[mi] = 0.f; bi[mi] = 0;   // all-zero -> argmax 0, ov 0 (matches ref)
    }
    bx1 = wave_min(bx1); by1 = wave_min(by1);
    bx2 = wave_max(bx2); by2 = wave_max(by2);
    int wid = tid >> 6, lid = tid & 63;
    if (lid == 0) wbb[wid] = make_float4(bx1, by1, bx2, by2);
    __syncthreads();
    if (tid < 64) {
        float ux1 = fminf(fminf(wbb[0].x, wbb[1].x), fminf(wbb[2].x, wbb[3].x));
        float uy1 = fminf(fminf(wbb[0].y, wbb[1].y), fminf(wbb[2].y, wbb[3].y));
        float ux2 = fmaxf(fmaxf(wbb[0].z, wbb[1].z), fmaxf(wbb[2].z, wbb[3].z));
        float uy2 = fmaxf(fmaxf(wbb[0].w, wbb[1].w), fmaxf(wbb[2].w, wbb[3].w));
        float4 t = t4[tid];
        bool pass = (fminf(t.z, ux2) - fmaxf(t.x, ux1) > 0.f) &&
                    (fminf(t.w, uy2) - fmaxf(t.y, uy1) > 0.f);
        unsigned long long mask = __ballot(pass);
        if (tid == 0) s_cnt = __popcll(mask);
        if (pass) {
            int pos = __popcll(mask & ((1ull << tid) - 1ull));
            alist[pos] = tid;          // ballot-compaction preserves increasing o
        }
    }
    __syncthreads();
    int cnt = s_cnt;
    for (int li = 0; li < cnt; ++li) {
        int o = alist[li];
        float4 t = t4[o];
        float w0 = fminf(t.z, bx2) - fmaxf(t.x, bx1);
        float h0 = fminf(t.w, by2) - fmaxf(t.y, by1);
        if (w0 <= 0.f || h0 <= 0.f) continue;   // wave-uniform refinement
        float area_a = ta[o];
#pragma unroll
        for (int mi = 0; mi < MULT; ++mi) {
            float iou = iou_pt(t, area_a, px1[mi], py1[mi], px2[mi], py2[mi], areab[mi]);
            if (iou > best[mi]) { best[mi] = iou; bi[mi] = o; }   // strict >: first max
        }
    }
    // per-prior epilogue (no override; kC2 fixes the <=64 scattered priors later)
    float ll = 0.f, llm = 0.f, cep = 0.f;
    int cp = 0, cp1 = 0;
#pragma unroll
    for (int mi = 0; mi < MULT; ++mi) {
        if (!act[mi]) continue;
        int p = p0 + mi * 256 + tid;
        int conf = (best[mi] >= THRESH) ? (int)lab[bi[mi]] : 0;   // label +-1.0 exact
        float2 c01 = ((const float2*)conf_data)[b * P + p];
        float c0 = c01.x, c1 = c01.y;
        float m = fmaxf(c0, c1);
        float lse = m + logf(expf(c0 - m) + expf(c1 - m));
        bool pos = conf != 0;
        float ce = lse - (pos ? c1 : c0);
        float rv = pos ? 0.f : ce;
        rank[(size_t)b * P + p] = rv;
        atomicAdd(&lhist[__float_as_uint(rv) >> HSHIFT], 1);
        if (pos) {
            cp++; cep += ce;
            int ti = bi[mi];
            float cx = pr4[mi].x, cy = pr4[mi].y, sw = pr4[mi].z, sh = pr4[mi].w;
            float4 t = t4[ti];
            float gx = ((t.x + t.z) * 0.5f - cx) / (0.1f * sw);
            float gy = ((t.y + t.w) * 0.5f - cy) / (0.1f * sh);
            float gw = logf((t.z - t.x) / sw) / 0.2f;
            float gh = logf((t.w - t.y) / sh) / 0.2f;
            const float* ld = &loc_data[(size_t)(b * P + p) * 4];
            ll += smooth_l1(ld[0] - gx) + smooth_l1(ld[1] - gy) +
                  smooth_l1(ld[2] - gw) + smooth_l1(ld[3] - gh);
            if (conf > 0) {
                cp1++;
                const float* lmd = &landm_data[(size_t)(b * P + p) * 10];
                for (int k5 = 0; k5 < 5; ++k5) {
                    float lx = (lm[ti][k5 * 2 + 0] - cx) / (0.1f * sw);
                    float ly = (lm[ti][k5 * 2 + 1] - cy) / (0.1f * sh);
                    llm += smooth_l1(lmd[k5 * 2 + 0] - lx) + smooth_l1(lmd[k5 * 2 + 1] - ly);
                }
            }
        }
    }
    float s_ll = wave_sum(ll), s_llm = wave_sum(llm), s_cep = wave_sum(cep);
    int s_cp = wave_sum_i(cp), s_cp1 = wave_sum_i(cp1);
    if (lid == 0) {
        wredf[0][wid] = s_ll; wredf[1][wid] = s_llm; wredf[2][wid] = s_cep;
        wredi[0][wid] = s_cp; wredi[1][wid] = s_cp1;
    }
    __syncthreads();
    if (tid == 0) {
        float ll_t = wredf[0][0] + wredf[0][1] + wredf[0][2] + wredf[0][3];
        float llm_t = wredf[1][0] + wredf[1][1] + wredf[1][2] + wredf[1][3];
        float cep_t = wredf[2][0] + wredf[2][1] + wredf[2][2] + wredf[2][3];
        int cp_t = wredi[0][0] + wredi[0][1] + wredi[0][2] + wredi[0][3];
        int cp1_t = wredi[1][0] + wredi[1][1] + wredi[1][2] + wredi[1][3];
        if (ll_t != 0.f)  atomicAdd(&gsum[0], ll_t);
        if (llm_t != 0.f) atomicAdd(&gsum[1], llm_t);
        if (cep_t != 0.f) atomicAdd(&pos_ce[b], cep_t);
        if (cp_t)  atomicAdd(&num_pos[b], cp_t);
        if (cp1_t) atomicAdd(np1_tot, cp1_t);
    }
    int* gh = hist + (size_t)b * HB;
#pragma unroll
    for (int i = tid; i < HB; i += 256) {
        int c = lhist[i];
        if (c) atomicAdd(&gh[i], c);
    }
}

// ---------------- Kernel C2 (fixup + findbin): dedup scatter (last j wins), recompute
// the <=64 overridden priors exactly, apply deltas; hist fixed in an LDS copy and the
// coarse bin selected here (kE0 merged). Row state is block-private after kD1.
__global__ void __launch_bounds__(256) kC2_fixup(
        const float* __restrict__ priors, const float* __restrict__ targets,
        const float* __restrict__ loc_data, const float* __restrict__ conf_data,
        const float* __restrict__ landm_data,
        const unsigned long long* __restrict__ bp_final,
        float* __restrict__ rank, const int* __restrict__ hist,
        int* __restrict__ num_pos, float* __restrict__ pos_ce,
        float* __restrict__ gsum, int* __restrict__ np1_tot, int* __restrict__ np_tot,
        int* __restrict__ binArr, int* __restrict__ kkArr) {
    int b = blockIdx.x;
    int tid = threadIdx.x;
    __shared__ float4 t4[O];
    __shared__ float ta[O], lab[O];
    __shared__ int sp[O];
    __shared__ int lh[HB];
    __shared__ int chunkSum[256];
    __shared__ int s_np;
    for (int i = tid; i < HB; i += 256) lh[i] = hist[(size_t)b * HB + i];
    int p = 0, v = 0;
    if (tid < O) {
        const float* tt = &targets[(b * O + tid) * 15];
        float4 tj = make_float4(tt[0], tt[1], tt[2], tt[3]);
        t4[tid] = tj;
        ta[tid] = (tj.z - tj.x) * (tj.w - tj.y);
        lab[tid] = tt[14];
        unsigned long long k = bp_final[b * O + tid];
        p = (int)(0xFFFFFFFFu - (unsigned)(k & 0xFFFFFFFFu));
        float iou = __uint_as_float((unsigned)(k >> 32));
        v = (iou >= VALID_T) ? 1 : 0;
        sp[tid] = p;
    }
    __syncthreads();
    int dnp = 0, dn1 = 0;
    float dll = 0.f, dllm = 0.f, dce = 0.f;
    if (tid < O) {
        int j = tid;
        bool winner = true;                // last j with this p wins (numpy scatter)
        for (int jj = j + 1; jj < O; ++jj)
            if (sp[jj] == p) { winner = false; break; }
        if (winner) {
            float4 q = ((const float4*)priors)[p];
            float px1 = q.x - q.z * 0.5f, py1 = q.y - q.w * 0.5f;
            float px2 = q.x + q.z * 0.5f, py2 = q.y + q.w * 0.5f;
            float areab = (px2 - px1) * (py2 - py1);
            float best = 0.f; int bi = 0;
            for (int o = 0; o < O; ++o) {
                float io = iou_pt(t4[o], ta[o], px1, py1, px2, py2, areab);
                if (io > best) { best = io; bi = o; }
            }
            float ov_new = v ? 2.0f : best;
            int conf_old = (best >= THRESH) ? (int)lab[bi] : 0;
            int conf_new = (ov_new >= THRESH) ? (int)lab[j] : 0;
            float2 c01 = ((const float2*)conf_data)[b * P + p];
            float c0 = c01.x, c1 = c01.y, m = fmaxf(c0, c1);
            float lse = m + logf(expf(c0 - m) + expf(c1 - m));
            bool po = conf_old != 0, pn = conf_new != 0;
            float ceo = lse - (po ? c1 : c0), cen = lse - (pn ? c1 : c0);
            float rvo = po ? 0.f : ceo, rvn = pn ? 0.f : cen;
            if (__float_as_uint(rvo) != __float_as_uint(rvn)) {
                rank[(size_t)b * P + p] = rvn;
                int bo = __float_as_uint(rvo) >> HSHIFT, bn = __float_as_uint(rvn) >> HSHIFT;
                if (bo != bn) { atomicAdd(&lh[bn], 1); atomicAdd(&lh[bo], -1); }
            }
            const float* ld = &loc_data[(size_t)(b * P + p) * 4];
            auto enc_ll = [&](int ti) -> float {    // same float ops as kD1 epilogue
                float4 t = t4[ti];
                float gx = ((t.x + t.z) * 0.5f - q.x) / (0.1f * q.z);
                float gy = ((t.y + t.w) * 0.5f - q.y) / (0.1f * q.w);
                float gw = logf((t.z - t.x) / q.z) / 0.2f;
                float gh = logf((t.w - t.y) / q.w) / 0.2f;
                return smooth_l1(ld[0] - gx) + smooth_l1(ld[1] - gy) +
                       smooth_l1(ld[2] - gw) + smooth_l1(ld[3] - gh);
            };
            if (po) dll -= enc_ll(bi);
            if (pn) dll += enc_ll(j);
            dce = (pn ? cen : 0.f) - (po ? ceo : 0.f);
            dnp = (int)pn - (int)po;
            const float* lmd = &landm_data[(size_t)(b * P + p) * 10];
            auto enc_lm = [&](int ti) -> float {
                const float* lmt = &targets[(b * O + ti) * 15 + 4];
                float sum = 0.f;
                for (int k5 = 0; k5 < 5; ++k5) {
                    float lx = (lmt[k5 * 2 + 0] - q.x) / (0.1f * q.z);
                    float ly = (lmt[k5 * 2 + 1] - q.y) / (0.1f * q.w);
                    sum += smooth_l1(lmd[k5 * 2 + 0] - lx) + smooth_l1(lmd[k5 * 2 + 1] - ly);
                }
                return sum;
            };
            if (conf_old > 0) dllm -= enc_lm(bi);
            if (conf_new > 0) dllm += enc_lm(j);
            dn1 = (int)(conf_new > 0) - (int)(conf_old > 0);
        }
    }
    if (tid < 64) {                        // wave 0 reduces the deltas
        float r_ll = wave_sum(dll), r_lm = wave_sum(dllm), r_ce = wave_sum(dce);
        int r_np = wave_sum_i(dnp), r_n1 = wave_sum_i(dn1);
        if (tid == 0) {
            if (r_ll != 0.f) atomicAdd(&gsum[0], r_ll);
            if (r_lm != 0.f) atomicAdd(&gsum[1], r_lm);
            if (r_ce != 0.f) pos_ce[b] += r_ce;        // row-private now
            int np = num_pos[b] + r_np;
            num_pos[b] = np;
            s_np = np;
            atomicAdd(np_tot, np);
            if (r_n1) atomicAdd(np1_tot, r_n1);
        }
    }
    __syncthreads();
    // ---- findbin (kE0 merged): hist is final in lh
    int k = s_np * 7;
    if (k > P - 1) k = P - 1;
    int cs = 0;
#pragma unroll
    for (int i = 0; i < HB / 256; ++i) cs += lh[tid * (HB / 256) + i];
    chunkSum[tid] = cs;
    __syncthreads();
    if (tid == 0) {
        if (k <= 0) { binArr[b] = -1; kkArr[b] = 0; return; }
        int cum = 0, bin = 0, kk = k;
        for (int c = 255; c >= 0; --c) {
            if (cum + chunkSum[c] >= k) {
                for (int i = HB / 256 - 1; i >= 0; --i) {
                    int hv = lh[c * (HB / 256) + i];
                    if (cum + hv >= k) { bin = c * (HB / 256) + i; kk = k - cum; goto found; }
                    cum += hv;
                }
            }
            cum += chunkSum[c];
        }
    found:
        binArr[b] = bin; kkArr[b] = kk;
    }
}

// ---------------- Kernel E1: parallel row scan — partial above-bin sum + candidate gather.
__global__ void kE1_scan(const float* __restrict__ rank, const int* __restrict__ binArr,
                         float* __restrict__ sumgt_part, unsigned* __restrict__ cand,
                         int* __restrict__ cand_cnt) {
    int seg = blockIdx.x % ESPLIT;
    int b = blockIdx.x / ESPLIT;
    int bin = binArr[b];
    if (bin < 0) return;
    const float* r = rank + (size_t)b * P;
    unsigned lo_bound = ((unsigned)(bin + 1)) << HSHIFT;
    __shared__ unsigned lc[PSEG];
    __shared__ int lcnt, gbase;
    __shared__ float wred[4];
    int t = threadIdx.x;
    if (t == 0) lcnt = 0;
    __syncthreads();
    int pend = min((seg + 1) * PSEG, P);
    float sumgt = 0.f;
    for (int p = seg * PSEG + t; p < pend; p += 256) {
        float v = r[p];
        unsigned u = __float_as_uint(v);
        if (u >= lo_bound) sumgt += v;
        else if ((u >> HSHIFT) == (unsigned)bin) {
            int idx = atomicAdd(&lcnt, 1);
            lc[idx] = u;
        }
    }
    __syncthreads();
    if (t == 0 && lcnt > 0) gbase = atomicAdd(&cand_cnt[b], lcnt);
    int wid = t >> 6, lid = t & 63;
    float s = wave_sum(sumgt);
    if (lid == 0) wred[wid] = s;
    __syncthreads();
    int n = lcnt, g0 = (n > 0) ? gbase : 0;
    for (int i = t; i < n; i += 256) {
        int d = g0 + i;
        if (d < CCAP) cand[(size_t)b * CCAP + d] = lc[i];
    }
    if (t == 0) {
        float tot = wred[0] + wred[1] + wred[2] + wred[3];
        if (tot != 0.f) atomicAdd(&sumgt_part[b], tot);
    }
}

// ---------------- Kernel E2: resolve remaining bits + final sum; LAST block writes out.
__global__ void kE2_resolve(const float* __restrict__ rank, const unsigned* __restrict__ cand,
                            const int* __restrict__ cand_cnt, const int* __restrict__ binArr,
                            const int* __restrict__ kkArr, const float* __restrict__ sumgt_part,
                            const float* __restrict__ pos_ce, float* __restrict__ gsum,
                            int* __restrict__ np_tot, int* __restrict__ np1_tot,
                            float* __restrict__ lossc_tot, int* __restrict__ done,
                            float* __restrict__ out) {
    int b = blockIdx.x;
    int bin = binArr[b];
    int t = threadIdx.x;
    __shared__ unsigned lcand[CCAP];
    __shared__ int hist2[256];
    __shared__ int s_bin, s_kk;
    __shared__ float redf[256];
    __shared__ int redi[256];
    float topk_b = 0.f;
    if (bin >= 0) {                      // block-uniform branch: __syncthreads safe
        int m = cand_cnt[b];
        int kk0 = kkArr[b];
        const unsigned* cd = cand + (size_t)b * CCAP;
        const float* r = rank + (size_t)b * P;
        bool useG = (m > CCAP);          // pathological overflow: rescan row
        if (!useG)
            for (int i = t; i < m; i += 256) lcand[i] = cd[i];
        __syncthreads();
        unsigned pref = ((unsigned)bin) << HSHIFT;
        unsigned resolved = 0xFFFFFFFFu << HSHIFT;
        int kk = kk0;
        const int shifts[3] = {13, 5, 0};
        const int nbins[3] = {256, 256, 32};
        for (int pass = 0; pass < 3; ++pass) {
            int sh = shifts[pass], nb = nbins[pass];
            for (int i = t; i < nb; i += 256) hist2[i] = 0;
            __syncthreads();
            if (!useG) {
                for (int i = t; i < m; i += 256) {
                    unsigned u = lcand[i];
                    if ((u & resolved) == pref) atomicAdd(&hist2[(u >> sh) & (nb - 1)], 1);
                }
            } else {
                for (int p = t; p < P; p += 256) {
                    unsigned u = __float_as_uint(r[p]);
                    if ((u & resolved) == pref) atomicAdd(&hist2[(u >> sh) & (nb - 1)], 1);
                }
            }
            __syncthreads();
            if (t == 0) {
                int cum = 0, d = 0, kn = kk;
                for (int i = nb - 1; i >= 0; --i) {
                    if (cum + hist2[i] >= kk) { d = i; kn = kk - cum; break; }
                    cum += hist2[i];
                }
                s_bin = d; s_kk = kn;
            }
            __syncthreads();
            pref |= ((unsigned)s_bin) << sh;
            resolved |= (unsigned)(nb - 1) << sh;
            kk = s_kk;
            __syncthreads();
        }
        float tv = __uint_as_float(pref);    // exact k-th largest value
        float sumS = 0.f; int cntS = 0;
        if (!useG) {
            for (int i = t; i < m; i += 256) {
                float v = __uint_as_float(lcand[i]);
                if (v > tv) { sumS += v; cntS++; }
            }
        } else {
            for (int p = t; p < P; p += 256) {
                unsigned u = __float_as_uint(r[p]);
                if ((u >> HSHIFT) == (unsigned)bin) {
                    float v = __uint_as_float(u);
                    if (v > tv) { sumS += v; cntS++; }
                }
            }
        }
        redf[t] = sumS; redi[t] = cntS; __syncthreads();
        for (int s = 128; s > 0; s >>= 1) {
            if (t < s) { redf[t] += redf[t + s]; redi[t] += redi[t + s]; }
            __syncthreads();
        }
        if (t == 0) topk_b = sumgt_part[b] + redf[0] + (float)(kk0 - redi[0]) * tv;
    }
    if (t == 0) {
        atomicAdd(lossc_tot, pos_ce[b] + topk_b);
        __threadfence();
        int old = atomicAdd(done, 1);
        if (old == B - 1) {              // last block finalizes (atomic reads: L2-fresh)
            float g0 = atomicAdd(&gsum[0], 0.f);
            float g1 = atomicAdd(&gsum[1], 0.f);
            float lc = atomicAdd(lossc_tot, 0.f);
            int np = atomicAdd(np_tot, 0);
            int n1 = atomicAdd(np1_tot, 0);
            float N = fmaxf((float)np, 1.f);
            float N1 = fmaxf((float)n1, 1.f);
            out[0] = g0 / N;
            out[1] = lc / N;
            out[2] = g1 / N1;
        }
    }
}

extern "C" void kernel_launch(void* const* d_in, const int* in_sizes, int n_in,
                              void* d_out, int out_size, void* d_ws, size_t ws_size,
                              hipStream_t stream) {
    const float* loc_data   = (const float*)d_in[0];
    const float* conf_data  = (const float*)d_in[1];
    const float* landm_data = (const float*)d_in[2];
    const float* priors     = (const float*)d_in[3];
    const float* targets    = (const float*)d_in[4];
    float* out = (float*)d_out;

    char* ws = (char*)d_ws;
    size_t off = 0;
    auto alloc = [&](size_t bytes) -> void* {
        void* p = ws + off;
        off += (bytes + 255) & ~(size_t)255;
        return p;
    };
    float* rank     = (float*)alloc((size_t)B * P * 4);
    unsigned long long* bp_final = (unsigned long long*)alloc((size_t)B * O * 8);
    unsigned* cand  = (unsigned*)alloc((size_t)B * CCAP * 4);
    int* binArr     = (int*)alloc(B * 4);
    int* kkArr      = (int*)alloc(B * 4);
    // zeroed region: hist + accumulators
    size_t hist_bytes = (size_t)B * HB * 4;
    char* zbase = (char*)alloc(hist_bytes);
    int* hist = (int*)zbase;
    size_t acc_bytes = (size_t)(B * 4 * 4 + 64);
    char* acc = (char*)alloc(acc_bytes);
    int*   num_pos      = (int*)acc;
    float* pos_ce       = (float*)(acc + B * 4);
    int*   cand_cnt     = (int*)(acc + 2 * B * 4);
    float* sumgt_part   = (float*)(acc + 3 * B * 4);
    float* gsum         = (float*)(acc + 4 * B * 4);       // 2 floats
    int*   np1_tot      = (int*)(acc + 4 * B * 4 + 8);
    int*   np_tot       = (int*)(acc + 4 * B * 4 + 12);
    float* lossc_tot    = (float*)(acc + 4 * B * 4 + 16);
    int*   done         = (int*)(acc + 4 * B * 4 + 20);
    size_t zlen = (size_t)(acc - zbase) + acc_bytes;

    hipMemsetAsync(zbase, 0, zlen, stream);

    kB2_best_prior<<<dim3(B * O), dim3(64), 0, stream>>>(priors, targets, bp_final);
    kD1_main<<<dim3(B * NB2), dim3(256), 0, stream>>>(loc_data, conf_data, landm_data, priors,
                                                      targets, rank, hist, num_pos, pos_ce,
                                                      gsum, np1_tot);
    kC2_fixup<<<dim3(B), dim3(256), 0, stream>>>(priors, targets, loc_data, conf_data,
                                                 landm_data, bp_final, rank, hist, num_pos,
                                                 pos_ce, gsum, np1_tot, np_tot, binArr, kkArr);
    kE1_scan<<<dim3(B * ESPLIT), dim3(256), 0, stream>>>(rank, binArr, sumgt_part, cand, cand_cnt);
    kE2_resolve<<<dim3(B), dim3(256), 0, stream>>>(rank, cand, cand_cnt, binArr, kkArr,
                                                   sumgt_part, pos_ce, gsum, np_tot, np1_tot,
                                                   lossc_tot, done, out);
}